// Round 11
// baseline (188.244 us; speedup 1.0000x reference)
//
#include <hip/hip_runtime.h>

#define NN 62
#define FF 5
#define KC 4
#define CO 64
#define NSEL 31
#define NF 310
#define NBATCH 4096
#define TPB 512        // 8 waves, 2/SIMD, one block/CU
#define BPB 16         // 8 waves x 2 batches
#define XS_ST 24       // xs row stride elems
#define XS_BY 48
#define AD_ST 72
#define AD_BY 144
#define WT_BY 80
#define U_BY  144

typedef __bf16 bf16x8 __attribute__((ext_vector_type(8)));
typedef __bf16 bf16x4 __attribute__((ext_vector_type(4)));
typedef float f32x4 __attribute__((ext_vector_type(4)));
typedef float f32x2 __attribute__((ext_vector_type(2)));
typedef unsigned short u16x8 __attribute__((ext_vector_type(8)));

#define MFMA(A, B, C) __builtin_amdgcn_mfma_f32_16x16x32_bf16((A), (B), (C), 0, 0, 0)

static __device__ __forceinline__ unsigned short f2bf(float f) {
    __bf16 b = (__bf16)f;
    return __builtin_bit_cast(unsigned short, b);
}
static __device__ __forceinline__ float bf2f(unsigned short s) {
    return __uint_as_float(((unsigned)s) << 16);
}
static __device__ __forceinline__ bf16x8 ldfrag(const unsigned short* p, int byte_off) {
    return *(const bf16x8*)((const char*)p + byte_off);
}

// launch_bounds(512, 2): 2 waves/EU == our single 8-wave block (LDS caps at 1 block/CU).
// Without it, hipcc budgets 512-thread kernels at the 128-VGPR quantum -> R10 spilled
// (VGPR pinned 128, FETCH 155MB, WRITE 299MB scratch). This raises the cap to 256.
__global__ __launch_bounds__(TPB, 2) void gnn_mfma(
    const float* __restrict__ x, const float* __restrict__ adj,
    const int* __restrict__ mask_idx,
    const float* __restrict__ gc_w, const float* __restrict__ gc_b,
    const float* __restrict__ gc1_w, const float* __restrict__ gc1_b,
    const float* __restrict__ gc2_w, const float* __restrict__ gc2_b,
    const float* __restrict__ fc1_w, const float* __restrict__ fc1_b,
    const float* __restrict__ fc2_w, const float* __restrict__ fc2_b,
    const float* __restrict__ cls_w, const float* __restrict__ cls_b,
    float* __restrict__ out)
{
    __shared__ __align__(16) unsigned short s_adjb[64 * AD_ST];      // 9216 B
    __shared__ __align__(16) unsigned short s_wt[3 * 64 * 40];       // 15360 B
    __shared__ __align__(16) unsigned short s_fc[64 * CO * 8];       // 65536 B, rows 62/63 zero
    __shared__ float s_bias[3][64];                                  // 768 B
    __shared__ float s_dis1[64];                                     // 256 B
    __shared__ float s_dis2[BPB][64];                                // 4096 B
    __shared__ unsigned s_mb[BPB][2];                                // 128 B
    __shared__ __align__(16) unsigned short s_ut[8][16 * AD_ST];     // 18432 B per-wave U^T
    __shared__ __align__(16) unsigned short s_xs[8 * 2 * 64 * XS_ST + 8]; // 49168 B
    // total 162960 B <= 163840

    const int t = threadIdx.x;
    const int w = t >> 6, lane = t & 63;
    const int g = lane >> 4, c = lane & 15;
    const int b0 = blockIdx.x * BPB;

    // ================= block-cooperative staging =================
    for (int i = t; i < 64 * AD_ST; i += TPB) {
        int r = i / AD_ST, cc = i - r * AD_ST;
        float v = (r < NN && cc < NN) ? adj[r * NN + cc] : 0.0f;
        s_adjb[i] = f2bf(v);
    }
    for (int i = t; i < 3 * 64 * 40; i += TPB) {
        int head = i / 2560, rem = i - head * 2560;
        int o = rem / 40, kf = rem - o * 40;
        const float* wp = (head == 0) ? gc1_w : (head == 1) ? gc2_w : gc_w;
        s_wt[i] = f2bf((kf < KC * FF) ? wp[kf * CO + o] : 0.0f);
    }
    for (int i = t; i < 64 * CO; i += TPB) {
        int r = i >> 6;
        u16x8 v;
        if (r < NN) {
            const float* f1p = fc1_w + i * 3;
            const float* f2p = fc2_w + i * 3;
            const float* fgp = cls_w + i * 2;
            v[0] = f2bf(f1p[0]); v[1] = f2bf(f1p[1]); v[2] = f2bf(f1p[2]);
            v[3] = f2bf(f2p[0]); v[4] = f2bf(f2p[1]); v[5] = f2bf(f2p[2]);
            v[6] = f2bf(fgp[0]); v[7] = f2bf(fgp[1]);
        } else {
            #pragma unroll
            for (int j = 0; j < 8; ++j) v[j] = (unsigned short)0;
        }
        *(u16x8*)&s_fc[i * 8] = v;
    }
    if (t < 192) {
        int head = t >> 6, o = t & 63;
        const float* bp = (head == 0) ? gc1_b : (head == 1) ? gc2_b : gc_b;
        s_bias[head][o] = bp[o];
    }
    if (t < BPB * 2) ((unsigned*)s_mb)[t] = 0u;
    if (t < 8) s_xs[8 * 2 * 64 * XS_ST + t] = 0;
    __syncthreads();   // B1

    for (int i = t; i < BPB * NSEL; i += TPB) {
        int bt = i / NSEL, s = i - bt * NSEL;
        int idx = mask_idx[(b0 + bt) * NSEL + s];
        atomicOr(&s_mb[bt][idx >> 5], 1u << (idx & 31));
    }
    __syncthreads();   // B2

    // ---- dis1/dis2 via MFMA on staged bf16 adj ----
    if (w < 4) {
        unsigned mlo = s_mb[c][0], mhi = s_mb[c][1];
        bf16x8 M0, M1;
        #pragma unroll
        for (int e = 0; e < 8; ++e) {
            int l = g * 8 + e;
            M0[e] = __builtin_bit_cast(__bf16, (unsigned short)(((mlo >> l) & 1u) ? 0x3F80 : 0));
            M1[e] = __builtin_bit_cast(__bf16, (unsigned short)(((mhi >> l) & 1u) ? 0x3F80 : 0));
        }
        bf16x8 A0 = ldfrag(s_adjb, (w * 16 + c) * AD_BY + g * 16);
        bf16x8 A1 = ldfrag(s_adjb, (w * 16 + c) * AD_BY + 64 + g * 16);
        f32x4 Cd = {0.f, 0.f, 0.f, 0.f};
        Cd = MFMA(A0, M0, Cd);
        Cd = MFMA(A1, M1, Cd);
        #pragma unroll
        for (int i = 0; i < 4; ++i) {
            int j = w * 16 + g * 4 + i;
            unsigned bit = (j < 32) ? ((mlo >> j) & 1u) : ((mhi >> (j - 32)) & 1u);
            float s = bit ? Cd[i] : 0.0f;
            s_dis2[c][j] = (s > 0.0f) ? rsqrtf(s) : 0.0f;
        }
    } else if (w == 4) {
        bf16x8 ones;
        #pragma unroll
        for (int e = 0; e < 8; ++e)
            ones[e] = __builtin_bit_cast(__bf16, (unsigned short)0x3F80);
        #pragma unroll
        for (int mt = 0; mt < 4; ++mt) {
            bf16x8 A0 = ldfrag(s_adjb, (mt * 16 + c) * AD_BY + g * 16);
            bf16x8 A1 = ldfrag(s_adjb, (mt * 16 + c) * AD_BY + 64 + g * 16);
            f32x4 Cd = {0.f, 0.f, 0.f, 0.f};
            Cd = MFMA(A0, ones, Cd);
            Cd = MFMA(A1, ones, Cd);
            if (c == 0) {
                #pragma unroll
                for (int i = 0; i < 4; ++i) {
                    float d = Cd[i];
                    s_dis1[mt * 16 + g * 4 + i] = (d > 0.0f) ? rsqrtf(d) : 0.0f;
                }
            }
        }
    }
    __syncthreads();   // B3 -- last barrier

    // ================= wave-private =================
    unsigned short* xsW0 = &s_xs[(w * 2 + 0) * 64 * XS_ST];
    unsigned short* xsW1 = &s_xs[(w * 2 + 1) * 64 * XS_ST];
    unsigned short* utW  = &s_ut[w][0];
    {
        unsigned* z = (unsigned*)xsW0;
        for (int i = lane; i < 64 * XS_ST; i += 64) z[i] = 0u;
        unsigned* zu = (unsigned*)utW;
        for (int i = lane; i < 16 * AD_ST / 2; i += 64) zu[i] = 0u;
    }

    float b1v[4], b2v[4], bgv[4];
    #pragma unroll
    for (int nt = 0; nt < 4; ++nt) {
        b1v[nt] = s_bias[0][nt * 16 + c];
        b2v[nt] = s_bias[1][nt * 16 + c];
        bgv[nt] = s_bias[2][nt * 16 + c];
    }

    bf16x8 adjA[4][2];
    #pragma unroll
    for (int mt = 0; mt < 4; ++mt)
        #pragma unroll
        for (int kf2 = 0; kf2 < 2; ++kf2)
            adjA[mt][kf2] = ldfrag(s_adjb, (mt * 16 + c) * AD_BY + kf2 * 64 + g * 16);

    const int f_c = (c < 5) ? c : (c < 10 ? c - 5 : 0);

    // ---- per-batch helpers ----
    auto stage_x = [&](int b, unsigned mlo, unsigned mhi) {
        const float* xb = x + (size_t)b * NF;
        #pragma unroll
        for (int it = 0; it < 5; ++it) {
            int e = lane + it * 64;
            if (e < NF) {
                int n = e / 5, f = e - n * 5;
                float v = xb[e];
                unsigned bit = (n < 32) ? ((mlo >> n) & 1u) : ((mhi >> (n - 32)) & 1u);
                xsW0[n * XS_ST + f] = f2bf(v);
                xsW1[n * XS_ST + f] = f2bf(bit ? v : 0.0f);
            }
        }
    };
    auto load_dsel = [&](int bb, float* dsel) {
        const float* dsp = (c < 5) ? s_dis1 : s_dis2[bb];
        #pragma unroll
        for (int mt = 0; mt < 4; ++mt)
            #pragma unroll
            for (int i = 0; i < 4; ++i)
                dsel[mt * 4 + i] = (c < 10) ? dsp[mt * 16 + g * 4 + i] : 0.0f;
    };
    auto load_xA = [&](f32x4* xA) {
        const unsigned short* xsp = (c >= 5 && c < 10) ? xsW1 : xsW0;
        #pragma unroll
        for (int mt = 0; mt < 4; ++mt)
            #pragma unroll
            for (int i = 0; i < 4; ++i)
                xA[mt][i] = (c < 10) ? bf2f(xsp[(mt * 16 + g * 4 + i) * XS_ST + f_c]) : 0.0f;
    };
    auto packU = [&](const float* dsel, const f32x4* v) {
        if (c < 10) {
            #pragma unroll
            for (int mt = 0; mt < 4; ++mt) {
                bf16x4 uv;
                uv[0] = (__bf16)(dsel[mt*4+0] * v[mt][0]);
                uv[1] = (__bf16)(dsel[mt*4+1] * v[mt][1]);
                uv[2] = (__bf16)(dsel[mt*4+2] * v[mt][2]);
                uv[3] = (__bf16)(dsel[mt*4+3] * v[mt][3]);
                *(bf16x4*)((char*)utW + c * U_BY + (mt * 16 + g * 4) * 2) = uv;
            }
        }
    };
    auto cheb_step = [&](int k, const float* dsel, f32x4* xA, f32x4* x1f) {
        const float cck = (k == 1) ? 1.0f : 2.0f;
        bf16x8 Uf0 = ldfrag(utW, c * U_BY + g * 16);
        bf16x8 Uf1 = ldfrag(utW, c * U_BY + 64 + g * 16);
        #pragma unroll
        for (int mt = 0; mt < 4; ++mt) {
            const f32x4 z = {0.f, 0.f, 0.f, 0.f};
            f32x4 Ca = MFMA(adjA[mt][0], Uf0, z);   // independent pair -> 2x ILP
            f32x4 Cb = MFMA(adjA[mt][1], Uf1, z);
            f32x4 Cv = Ca + Cb;
            f32x4 xn;
            #pragma unroll
            for (int i = 0; i < 4; ++i) {
                float vv = -cck * dsel[mt * 4 + i] * Cv[i];
                if (k == 2) vv -= xA[mt][i];
                if (k == 3) vv -= x1f[mt][i];
                xn[i] = vv;
            }
            if (c < 10) {
                unsigned short* dst = (c < 5) ? xsW0 : xsW1;
                #pragma unroll
                for (int i = 0; i < 4; ++i)
                    dst[(mt * 16 + g * 4 + i) * XS_ST + k * 5 + f_c] = f2bf(xn[i]);
                if (k < 3) {
                    bf16x4 uv;
                    uv[0] = (__bf16)(dsel[mt*4+0] * xn[0]);
                    uv[1] = (__bf16)(dsel[mt*4+1] * xn[1]);
                    uv[2] = (__bf16)(dsel[mt*4+2] * xn[2]);
                    uv[3] = (__bf16)(dsel[mt*4+3] * xn[3]);
                    *(bf16x4*)((char*)utW + c * U_BY + (mt * 16 + g * 4) * 2) = uv;
                }
            }
            if (k == 1) x1f[mt] = xn;
        }
    };
    // branch-free epilogue group (rows 62/63: xs==0 exactly, fc rows zeroed)
    auto epi_group = [&](int nt, const bf16x8* A1, const bf16x8* A2, f32x2* ap) {
        bf16x8 W1f = ldfrag(s_wt, (0 * 64 + nt * 16 + c) * WT_BY + g * 16);
        bf16x8 W2f = ldfrag(s_wt, (1 * 64 + nt * 16 + c) * WT_BY + g * 16);
        bf16x8 Wgf = ldfrag(s_wt, (2 * 64 + nt * 16 + c) * WT_BY + g * 16);
        const f32x2 bb12 = { b1v[nt], b2v[nt] };
        const float bbg = bgv[nt];
        #pragma unroll
        for (int mt = 0; mt < 4; ++mt) {
            const f32x4 z = {0.f, 0.f, 0.f, 0.f};
            f32x4 C1 = MFMA(A1[mt], W1f, z);
            f32x4 C2 = MFMA(A2[mt], W2f, z);
            f32x4 Cg = MFMA(A1[mt], Wgf, z);
            #pragma unroll
            for (int i = 0; i < 4; ++i) {
                int r = mt * 16 + g * 4 + i;
                const u16x8 fcv = *(const u16x8*)((const char*)s_fc +
                                    ((r * CO + nt * 16 + c) << 4));
                f32x2 h12 = f32x2{C1[i], C2[i]} + bb12;
                h12.x = fmaxf(h12.x, 0.f);
                h12.y = fmaxf(h12.y, 0.f);
                float hg = fmaxf(Cg[i] + bbg, 0.f);
                ap[0] += f32x2{h12.x, h12.x} * f32x2{bf2f(fcv[0]), bf2f(fcv[1])};
                ap[1] += f32x2{h12.x, h12.y} * f32x2{bf2f(fcv[2]), bf2f(fcv[3])};
                ap[2] += f32x2{h12.y, h12.y} * f32x2{bf2f(fcv[4]), bf2f(fcv[5])};
                ap[3] += f32x2{hg,    hg   } * f32x2{bf2f(fcv[6]), bf2f(fcv[7])};
            }
        }
    };

    const int bb0 = w * 2, bb1 = w * 2 + 1;
    f32x2 acc0[4], acc1[4];
    #pragma unroll
    for (int q = 0; q < 4; ++q) { acc0[q] = f32x2{0.f, 0.f}; acc1[q] = f32x2{0.f, 0.f}; }

    float dsel0[16], dsel1[16];
    f32x4 xA0[4], x1f0[4], xA1[4], x1f1[4];
    bf16x8 A1f0[4], A2f0[4], A1f1[4], A2f1[4];

    // ---- batch 0: full cheb, A-frags ----
    stage_x(b0 + bb0, s_mb[bb0][0], s_mb[bb0][1]);
    load_dsel(bb0, dsel0);
    load_xA(xA0);
    packU(dsel0, xA0);
    cheb_step(1, dsel0, xA0, x1f0);
    cheb_step(2, dsel0, xA0, x1f0);
    cheb_step(3, dsel0, xA0, x1f0);
    #pragma unroll
    for (int mt = 0; mt < 4; ++mt) {
        A1f0[mt] = ldfrag(xsW0, (mt * 16 + c) * XS_BY + g * 16);
        A2f0[mt] = ldfrag(xsW1, (mt * 16 + c) * XS_BY + g * 16);
    }

    // ---- batch 1 prep (xs overwrite OK: b0 frags in regs) ----
    stage_x(b0 + bb1, s_mb[bb1][0], s_mb[bb1][1]);
    load_dsel(bb1, dsel1);
    load_xA(xA1);
    packU(dsel1, xA1);

    // ---- software pipeline: cheb(b1) k-steps interleaved with epilogue(b0) ----
    cheb_step(1, dsel1, xA1, x1f1);
    epi_group(0, A1f0, A2f0, acc0);
    cheb_step(2, dsel1, xA1, x1f1);
    epi_group(1, A1f0, A2f0, acc0);
    cheb_step(3, dsel1, xA1, x1f1);
    epi_group(2, A1f0, A2f0, acc0);
    #pragma unroll
    for (int mt = 0; mt < 4; ++mt) {
        A1f1[mt] = ldfrag(xsW0, (mt * 16 + c) * XS_BY + g * 16);
        A2f1[mt] = ldfrag(xsW1, (mt * 16 + c) * XS_BY + g * 16);
    }
    epi_group(3, A1f0, A2f0, acc0);
    epi_group(0, A1f1, A2f1, acc1);
    epi_group(1, A1f1, A2f1, acc1);
    epi_group(2, A1f1, A2f1, acc1);
    epi_group(3, A1f1, A2f1, acc1);

    // ---- wave reduction + output ----
    float red[16] = {
        acc0[0].x, acc0[0].y, acc0[1].x, acc0[1].y,
        acc0[2].x, acc0[2].y, acc0[3].x, acc0[3].y,
        acc1[0].x, acc1[0].y, acc1[1].x, acc1[1].y,
        acc1[2].x, acc1[2].y, acc1[3].x, acc1[3].y
    };
    #pragma unroll
    for (int off = 32; off > 0; off >>= 1)
        #pragma unroll
        for (int q = 0; q < 16; ++q)
            red[q] += __shfl_down(red[q], off);

    if (lane == 0) {
        #pragma unroll
        for (int bi = 0; bi < 2; ++bi) {
            const int b = b0 + w * 2 + bi;
            const float* r = &red[bi * 8];
            float l0 = r[0] + fc1_b[0];
            float l1 = r[1] + fc1_b[1];
            float l2 = r[2] + fc1_b[2];
            float m0 = r[3] + fc2_b[0];
            float m1 = r[4] + fc2_b[1];
            float m2 = r[5] + fc2_b[2];
            float g0 = r[6] + cls_b[0];
            float g1 = r[7] + cls_b[1];
            float mx = fmaxf(g0, g1);
            float e0 = expf(g0 - mx), e1 = expf(g1 - mx);
            float inv = 1.0f / (e0 + e1);
            float p0 = e0 * inv, p1 = e1 * inv;
            out[b * 3 + 0] = l0 * p0 + m0 * p1;
            out[b * 3 + 1] = l1 * p0 + m1 * p1;
            out[b * 3 + 2] = l2 * p0 + m2 * p1;
        }
    }
}

extern "C" void kernel_launch(void* const* d_in, const int* in_sizes, int n_in,
                              void* d_out, int out_size, void* d_ws, size_t ws_size,
                              hipStream_t stream) {
    const float* x      = (const float*)d_in[0];
    const float* adj    = (const float*)d_in[1];
    const int*   midx   = (const int*)  d_in[2];
    const float* gc_w   = (const float*)d_in[3];
    const float* gc_b   = (const float*)d_in[4];
    const float* gc1_w  = (const float*)d_in[5];
    const float* gc1_b  = (const float*)d_in[6];
    const float* gc2_w  = (const float*)d_in[7];
    const float* gc2_b  = (const float*)d_in[8];
    const float* fc1_w  = (const float*)d_in[9];
    const float* fc1_b  = (const float*)d_in[10];
    const float* fc2_w  = (const float*)d_in[11];
    const float* fc2_b  = (const float*)d_in[12];
    const float* cls_w  = (const float*)d_in[13];
    const float* cls_b  = (const float*)d_in[14];
    float* o = (float*)d_out;
    hipLaunchKernelGGL(gnn_mfma, dim3(NBATCH / BPB), dim3(TPB), 0, stream,
        x, adj, midx, gc_w, gc_b, gc1_w, gc1_b, gc2_w, gc2_b,
        fc1_w, fc1_b, fc2_w, fc2_b, cls_w, cls_b, o);
}

// Round 12
// 182.655 us; speedup vs baseline: 1.0306x; 1.0306x over previous
//
#include <hip/hip_runtime.h>

#define NN 62
#define FF 5
#define KC 4
#define CO 64
#define NSEL 31
#define NF 310
#define NBATCH 4096
#define TPB 512        // 8 waves, 2/SIMD, one block/CU
#define BPB 16         // 8 waves x 2 batches
#define XS_ST 24       // xs row stride elems
#define XS_BY 48
#define AD_ST 72
#define AD_BY 144
#define WT_BY 80
#define U_BY  144

typedef __bf16 bf16x8 __attribute__((ext_vector_type(8)));
typedef __bf16 bf16x4 __attribute__((ext_vector_type(4)));
typedef float f32x4 __attribute__((ext_vector_type(4)));
typedef float f32x2 __attribute__((ext_vector_type(2)));
typedef unsigned short u16x8 __attribute__((ext_vector_type(8)));

#define MFMA(A, B, C) __builtin_amdgcn_mfma_f32_16x16x32_bf16((A), (B), (C), 0, 0, 0)

static __device__ __forceinline__ unsigned short f2bf(float f) {
    __bf16 b = (__bf16)f;
    return __builtin_bit_cast(unsigned short, b);
}
static __device__ __forceinline__ float bf2f(unsigned short s) {
    return __uint_as_float(((unsigned)s) << 16);
}
static __device__ __forceinline__ bf16x8 ldfrag(const unsigned short* p, int byte_off) {
    return *(const bf16x8*)((const char*)p + byte_off);
}

// launch_bounds 2nd arg is CUDA-style MIN BLOCKS/CU on this toolchain (evidence:
// (320,4)->64 VGPR cap, (512,2)->128 cap == 512/(blocks*waves/4)). With 1 block
// of 8 waves: 2 waves/EU -> 256-VGPR quantum. LDS already caps us at 1 block/CU.
__global__ __launch_bounds__(TPB, 1) void gnn_mfma(
    const float* __restrict__ x, const float* __restrict__ adj,
    const int* __restrict__ mask_idx,
    const float* __restrict__ gc_w, const float* __restrict__ gc_b,
    const float* __restrict__ gc1_w, const float* __restrict__ gc1_b,
    const float* __restrict__ gc2_w, const float* __restrict__ gc2_b,
    const float* __restrict__ fc1_w, const float* __restrict__ fc1_b,
    const float* __restrict__ fc2_w, const float* __restrict__ fc2_b,
    const float* __restrict__ cls_w, const float* __restrict__ cls_b,
    float* __restrict__ out)
{
    __shared__ __align__(16) unsigned short s_adjb[64 * AD_ST];      // 9216 B
    __shared__ __align__(16) unsigned short s_wt[3 * 64 * 40];       // 15360 B
    __shared__ __align__(16) unsigned short s_fc[64 * CO * 8];       // 65536 B, rows 62/63 zero
    __shared__ float s_bias[3][64];                                  // 768 B
    __shared__ float s_dis1[64];                                     // 256 B
    __shared__ float s_dis2[BPB][64];                                // 4096 B
    __shared__ unsigned s_mb[BPB][2];                                // 128 B
    __shared__ __align__(16) unsigned short s_ut[8][16 * AD_ST];     // 18432 B per-wave U^T
    __shared__ __align__(16) unsigned short s_xs[8 * 2 * 64 * XS_ST + 8]; // 49168 B
    // total 162960 B <= 163840

    const int t = threadIdx.x;
    const int w = t >> 6, lane = t & 63;
    const int g = lane >> 4, c = lane & 15;
    const int b0 = blockIdx.x * BPB;

    // ================= block-cooperative staging =================
    for (int i = t; i < 64 * AD_ST; i += TPB) {
        int r = i / AD_ST, cc = i - r * AD_ST;
        float v = (r < NN && cc < NN) ? adj[r * NN + cc] : 0.0f;
        s_adjb[i] = f2bf(v);
    }
    for (int i = t; i < 3 * 64 * 40; i += TPB) {
        int head = i / 2560, rem = i - head * 2560;
        int o = rem / 40, kf = rem - o * 40;
        const float* wp = (head == 0) ? gc1_w : (head == 1) ? gc2_w : gc_w;
        s_wt[i] = f2bf((kf < KC * FF) ? wp[kf * CO + o] : 0.0f);
    }
    for (int i = t; i < 64 * CO; i += TPB) {
        int r = i >> 6;
        u16x8 v;
        if (r < NN) {
            const float* f1p = fc1_w + i * 3;
            const float* f2p = fc2_w + i * 3;
            const float* fgp = cls_w + i * 2;
            v[0] = f2bf(f1p[0]); v[1] = f2bf(f1p[1]); v[2] = f2bf(f1p[2]);
            v[3] = f2bf(f2p[0]); v[4] = f2bf(f2p[1]); v[5] = f2bf(f2p[2]);
            v[6] = f2bf(fgp[0]); v[7] = f2bf(fgp[1]);
        } else {
            #pragma unroll
            for (int j = 0; j < 8; ++j) v[j] = (unsigned short)0;
        }
        *(u16x8*)&s_fc[i * 8] = v;
    }
    if (t < 192) {
        int head = t >> 6, o = t & 63;
        const float* bp = (head == 0) ? gc1_b : (head == 1) ? gc2_b : gc_b;
        s_bias[head][o] = bp[o];
    }
    if (t < BPB * 2) ((unsigned*)s_mb)[t] = 0u;
    if (t < 8) s_xs[8 * 2 * 64 * XS_ST + t] = 0;
    __syncthreads();   // B1

    for (int i = t; i < BPB * NSEL; i += TPB) {
        int bt = i / NSEL, s = i - bt * NSEL;
        int idx = mask_idx[(b0 + bt) * NSEL + s];
        atomicOr(&s_mb[bt][idx >> 5], 1u << (idx & 31));
    }
    __syncthreads();   // B2

    // ---- dis1/dis2 via MFMA on staged bf16 adj ----
    if (w < 4) {
        unsigned mlo = s_mb[c][0], mhi = s_mb[c][1];
        bf16x8 M0, M1;
        #pragma unroll
        for (int e = 0; e < 8; ++e) {
            int l = g * 8 + e;
            M0[e] = __builtin_bit_cast(__bf16, (unsigned short)(((mlo >> l) & 1u) ? 0x3F80 : 0));
            M1[e] = __builtin_bit_cast(__bf16, (unsigned short)(((mhi >> l) & 1u) ? 0x3F80 : 0));
        }
        bf16x8 A0 = ldfrag(s_adjb, (w * 16 + c) * AD_BY + g * 16);
        bf16x8 A1 = ldfrag(s_adjb, (w * 16 + c) * AD_BY + 64 + g * 16);
        f32x4 Cd = {0.f, 0.f, 0.f, 0.f};
        Cd = MFMA(A0, M0, Cd);
        Cd = MFMA(A1, M1, Cd);
        #pragma unroll
        for (int i = 0; i < 4; ++i) {
            int j = w * 16 + g * 4 + i;
            unsigned bit = (j < 32) ? ((mlo >> j) & 1u) : ((mhi >> (j - 32)) & 1u);
            float s = bit ? Cd[i] : 0.0f;
            s_dis2[c][j] = (s > 0.0f) ? rsqrtf(s) : 0.0f;
        }
    } else if (w == 4) {
        bf16x8 ones;
        #pragma unroll
        for (int e = 0; e < 8; ++e)
            ones[e] = __builtin_bit_cast(__bf16, (unsigned short)0x3F80);
        #pragma unroll
        for (int mt = 0; mt < 4; ++mt) {
            bf16x8 A0 = ldfrag(s_adjb, (mt * 16 + c) * AD_BY + g * 16);
            bf16x8 A1 = ldfrag(s_adjb, (mt * 16 + c) * AD_BY + 64 + g * 16);
            f32x4 Cd = {0.f, 0.f, 0.f, 0.f};
            Cd = MFMA(A0, ones, Cd);
            Cd = MFMA(A1, ones, Cd);
            if (c == 0) {
                #pragma unroll
                for (int i = 0; i < 4; ++i) {
                    float d = Cd[i];
                    s_dis1[mt * 16 + g * 4 + i] = (d > 0.0f) ? rsqrtf(d) : 0.0f;
                }
            }
        }
    }
    __syncthreads();   // B3 -- last barrier

    // ================= wave-private =================
    unsigned short* xsW0 = &s_xs[(w * 2 + 0) * 64 * XS_ST];
    unsigned short* xsW1 = &s_xs[(w * 2 + 1) * 64 * XS_ST];
    unsigned short* utW  = &s_ut[w][0];
    {
        unsigned* z = (unsigned*)xsW0;
        for (int i = lane; i < 64 * XS_ST; i += 64) z[i] = 0u;
        unsigned* zu = (unsigned*)utW;
        for (int i = lane; i < 16 * AD_ST / 2; i += 64) zu[i] = 0u;
    }

    float b1v[4], b2v[4], bgv[4];
    #pragma unroll
    for (int nt = 0; nt < 4; ++nt) {
        b1v[nt] = s_bias[0][nt * 16 + c];
        b2v[nt] = s_bias[1][nt * 16 + c];
        bgv[nt] = s_bias[2][nt * 16 + c];
    }

    const int f_c = (c < 5) ? c : (c < 10 ? c - 5 : 0);

    // ---- per-batch helpers ----
    auto stage_x = [&](int b, unsigned mlo, unsigned mhi) {
        const float* xb = x + (size_t)b * NF;
        #pragma unroll
        for (int it = 0; it < 5; ++it) {
            int e = lane + it * 64;
            if (e < NF) {
                int n = e / 5, f = e - n * 5;
                float v = xb[e];
                unsigned bit = (n < 32) ? ((mlo >> n) & 1u) : ((mhi >> (n - 32)) & 1u);
                xsW0[n * XS_ST + f] = f2bf(v);
                xsW1[n * XS_ST + f] = f2bf(bit ? v : 0.0f);
            }
        }
    };
    auto load_dsel = [&](int bb, float* dsel) {
        const float* dsp = (c < 5) ? s_dis1 : s_dis2[bb];
        #pragma unroll
        for (int mt = 0; mt < 4; ++mt)
            #pragma unroll
            for (int i = 0; i < 4; ++i)
                dsel[mt * 4 + i] = (c < 10) ? dsp[mt * 16 + g * 4 + i] : 0.0f;
    };
    auto load_xA = [&](f32x4* xA) {
        const unsigned short* xsp = (c >= 5 && c < 10) ? xsW1 : xsW0;
        #pragma unroll
        for (int mt = 0; mt < 4; ++mt)
            #pragma unroll
            for (int i = 0; i < 4; ++i)
                xA[mt][i] = (c < 10) ? bf2f(xsp[(mt * 16 + g * 4 + i) * XS_ST + f_c]) : 0.0f;
    };
    auto packU = [&](const float* dsel, const f32x4* v) {
        if (c < 10) {
            #pragma unroll
            for (int mt = 0; mt < 4; ++mt) {
                bf16x4 uv;
                uv[0] = (__bf16)(dsel[mt*4+0] * v[mt][0]);
                uv[1] = (__bf16)(dsel[mt*4+1] * v[mt][1]);
                uv[2] = (__bf16)(dsel[mt*4+2] * v[mt][2]);
                uv[3] = (__bf16)(dsel[mt*4+3] * v[mt][3]);
                *(bf16x4*)((char*)utW + c * U_BY + (mt * 16 + g * 4) * 2) = uv;
            }
        }
    };
    // adj fragments re-read from LDS per step (saves 32 live VGPRs vs caching)
    auto cheb_step = [&](int k, const float* dsel, f32x4* xA, f32x4* x1f) {
        const float cck = (k == 1) ? 1.0f : 2.0f;
        bf16x8 Uf0 = ldfrag(utW, c * U_BY + g * 16);
        bf16x8 Uf1 = ldfrag(utW, c * U_BY + 64 + g * 16);
        #pragma unroll
        for (int mt = 0; mt < 4; ++mt) {
            bf16x8 adj0 = ldfrag(s_adjb, (mt * 16 + c) * AD_BY + g * 16);
            bf16x8 adj1 = ldfrag(s_adjb, (mt * 16 + c) * AD_BY + 64 + g * 16);
            const f32x4 z = {0.f, 0.f, 0.f, 0.f};
            f32x4 Ca = MFMA(adj0, Uf0, z);   // independent pair -> 2x ILP
            f32x4 Cb = MFMA(adj1, Uf1, z);
            f32x4 Cv = Ca + Cb;
            f32x4 xn;
            #pragma unroll
            for (int i = 0; i < 4; ++i) {
                float vv = -cck * dsel[mt * 4 + i] * Cv[i];
                if (k == 2) vv -= xA[mt][i];
                if (k == 3) vv -= x1f[mt][i];
                xn[i] = vv;
            }
            if (c < 10) {
                unsigned short* dst = (c < 5) ? xsW0 : xsW1;
                #pragma unroll
                for (int i = 0; i < 4; ++i)
                    dst[(mt * 16 + g * 4 + i) * XS_ST + k * 5 + f_c] = f2bf(xn[i]);
                if (k < 3) {
                    bf16x4 uv;
                    uv[0] = (__bf16)(dsel[mt*4+0] * xn[0]);
                    uv[1] = (__bf16)(dsel[mt*4+1] * xn[1]);
                    uv[2] = (__bf16)(dsel[mt*4+2] * xn[2]);
                    uv[3] = (__bf16)(dsel[mt*4+3] * xn[3]);
                    *(bf16x4*)((char*)utW + c * U_BY + (mt * 16 + g * 4) * 2) = uv;
                }
            }
            if (k == 1) x1f[mt] = xn;
        }
    };
    // branch-free epilogue group (rows 62/63: xs==0 exactly, fc rows zeroed)
    auto epi_group = [&](int nt, const bf16x8* A1, const bf16x8* A2, f32x2* ap) {
        bf16x8 W1f = ldfrag(s_wt, (0 * 64 + nt * 16 + c) * WT_BY + g * 16);
        bf16x8 W2f = ldfrag(s_wt, (1 * 64 + nt * 16 + c) * WT_BY + g * 16);
        bf16x8 Wgf = ldfrag(s_wt, (2 * 64 + nt * 16 + c) * WT_BY + g * 16);
        const f32x2 bb12 = { b1v[nt], b2v[nt] };
        const float bbg = bgv[nt];
        #pragma unroll
        for (int mt = 0; mt < 4; ++mt) {
            const f32x4 z = {0.f, 0.f, 0.f, 0.f};
            f32x4 C1 = MFMA(A1[mt], W1f, z);
            f32x4 C2 = MFMA(A2[mt], W2f, z);
            f32x4 Cg = MFMA(A1[mt], Wgf, z);
            #pragma unroll
            for (int i = 0; i < 4; ++i) {
                int r = mt * 16 + g * 4 + i;
                const u16x8 fcv = *(const u16x8*)((const char*)s_fc +
                                    ((r * CO + nt * 16 + c) << 4));
                f32x2 h12 = f32x2{C1[i], C2[i]} + bb12;
                h12.x = fmaxf(h12.x, 0.f);
                h12.y = fmaxf(h12.y, 0.f);
                float hg = fmaxf(Cg[i] + bbg, 0.f);
                ap[0] += f32x2{h12.x, h12.x} * f32x2{bf2f(fcv[0]), bf2f(fcv[1])};
                ap[1] += f32x2{h12.x, h12.y} * f32x2{bf2f(fcv[2]), bf2f(fcv[3])};
                ap[2] += f32x2{h12.y, h12.y} * f32x2{bf2f(fcv[4]), bf2f(fcv[5])};
                ap[3] += f32x2{hg,    hg   } * f32x2{bf2f(fcv[6]), bf2f(fcv[7])};
            }
        }
    };

    const int bb0 = w * 2, bb1 = w * 2 + 1;
    f32x2 acc0[4], acc1[4];
    #pragma unroll
    for (int q = 0; q < 4; ++q) { acc0[q] = f32x2{0.f, 0.f}; acc1[q] = f32x2{0.f, 0.f}; }

    float dsel0[16], dsel1[16];
    f32x4 xA0[4], x1f0[4], xA1[4], x1f1[4];
    bf16x8 A1f0[4], A2f0[4], A1f1[4], A2f1[4];

    // ---- batch 0: full cheb, A-frags ----
    stage_x(b0 + bb0, s_mb[bb0][0], s_mb[bb0][1]);
    load_dsel(bb0, dsel0);
    load_xA(xA0);
    packU(dsel0, xA0);
    cheb_step(1, dsel0, xA0, x1f0);
    cheb_step(2, dsel0, xA0, x1f0);
    cheb_step(3, dsel0, xA0, x1f0);
    #pragma unroll
    for (int mt = 0; mt < 4; ++mt) {
        A1f0[mt] = ldfrag(xsW0, (mt * 16 + c) * XS_BY + g * 16);
        A2f0[mt] = ldfrag(xsW1, (mt * 16 + c) * XS_BY + g * 16);
    }

    // ---- batch 1 prep (xs overwrite OK: b0 frags in regs) ----
    stage_x(b0 + bb1, s_mb[bb1][0], s_mb[bb1][1]);
    load_dsel(bb1, dsel1);
    load_xA(xA1);
    packU(dsel1, xA1);

    // ---- software pipeline: cheb(b1) k-steps interleaved with epilogue(b0) ----
    cheb_step(1, dsel1, xA1, x1f1);
    epi_group(0, A1f0, A2f0, acc0);
    cheb_step(2, dsel1, xA1, x1f1);
    epi_group(1, A1f0, A2f0, acc0);
    cheb_step(3, dsel1, xA1, x1f1);
    epi_group(2, A1f0, A2f0, acc0);
    #pragma unroll
    for (int mt = 0; mt < 4; ++mt) {
        A1f1[mt] = ldfrag(xsW0, (mt * 16 + c) * XS_BY + g * 16);
        A2f1[mt] = ldfrag(xsW1, (mt * 16 + c) * XS_BY + g * 16);
    }
    epi_group(3, A1f0, A2f0, acc0);
    epi_group(0, A1f1, A2f1, acc1);
    epi_group(1, A1f1, A2f1, acc1);
    epi_group(2, A1f1, A2f1, acc1);
    epi_group(3, A1f1, A2f1, acc1);

    // ---- wave reduction + output ----
    float red[16] = {
        acc0[0].x, acc0[0].y, acc0[1].x, acc0[1].y,
        acc0[2].x, acc0[2].y, acc0[3].x, acc0[3].y,
        acc1[0].x, acc1[0].y, acc1[1].x, acc1[1].y,
        acc1[2].x, acc1[2].y, acc1[3].x, acc1[3].y
    };
    #pragma unroll
    for (int off = 32; off > 0; off >>= 1)
        #pragma unroll
        for (int q = 0; q < 16; ++q)
            red[q] += __shfl_down(red[q], off);

    if (lane == 0) {
        #pragma unroll
        for (int bi = 0; bi < 2; ++bi) {
            const int b = b0 + w * 2 + bi;
            const float* r = &red[bi * 8];
            float l0 = r[0] + fc1_b[0];
            float l1 = r[1] + fc1_b[1];
            float l2 = r[2] + fc1_b[2];
            float m0 = r[3] + fc2_b[0];
            float m1 = r[4] + fc2_b[1];
            float m2 = r[5] + fc2_b[2];
            float g0 = r[6] + cls_b[0];
            float g1 = r[7] + cls_b[1];
            float mx = fmaxf(g0, g1);
            float e0 = expf(g0 - mx), e1 = expf(g1 - mx);
            float inv = 1.0f / (e0 + e1);
            float p0 = e0 * inv, p1 = e1 * inv;
            out[b * 3 + 0] = l0 * p0 + m0 * p1;
            out[b * 3 + 1] = l1 * p0 + m1 * p1;
            out[b * 3 + 2] = l2 * p0 + m2 * p1;
        }
    }
}

extern "C" void kernel_launch(void* const* d_in, const int* in_sizes, int n_in,
                              void* d_out, int out_size, void* d_ws, size_t ws_size,
                              hipStream_t stream) {
    const float* x      = (const float*)d_in[0];
    const float* adj    = (const float*)d_in[1];
    const int*   midx   = (const int*)  d_in[2];
    const float* gc_w   = (const float*)d_in[3];
    const float* gc_b   = (const float*)d_in[4];
    const float* gc1_w  = (const float*)d_in[5];
    const float* gc1_b  = (const float*)d_in[6];
    const float* gc2_w  = (const float*)d_in[7];
    const float* gc2_b  = (const float*)d_in[8];
    const float* fc1_w  = (const float*)d_in[9];
    const float* fc1_b  = (const float*)d_in[10];
    const float* fc2_w  = (const float*)d_in[11];
    const float* fc2_b  = (const float*)d_in[12];
    const float* cls_w  = (const float*)d_in[13];
    const float* cls_b  = (const float*)d_in[14];
    float* o = (float*)d_out;
    hipLaunchKernelGGL(gnn_mfma, dim3(NBATCH / BPB), dim3(TPB), 0, stream,
        x, adj, midx, gc_w, gc_b, gc1_w, gc1_b, gc2_w, gc2_b,
        fc1_w, fc1_b, fc2_w, fc2_b, cls_w, cls_b, o);
}

// Round 13
// 74.045 us; speedup vs baseline: 2.5423x; 2.4668x over previous
//
#include <hip/hip_runtime.h>

#define NN 62
#define FF 5
#define KC 4
#define CO 64
#define NSEL 31
#define NF 310
#define NBATCH 4096
#define TPB 512        // 8 waves, 2/SIMD, one block/CU
#define BPB 16         // 8 waves x 2 batches
#define XS_ST 24       // xs row stride elems
#define XS_BY 48
#define AD_ST 72
#define AD_BY 144
#define WT_BY 80
#define U_BY  144

typedef __bf16 bf16x8 __attribute__((ext_vector_type(8)));
typedef __bf16 bf16x4 __attribute__((ext_vector_type(4)));
typedef float f32x4 __attribute__((ext_vector_type(4)));
typedef float f32x2 __attribute__((ext_vector_type(2)));
typedef unsigned short u16x8 __attribute__((ext_vector_type(8)));

#define MFMA(A, B, C) __builtin_amdgcn_mfma_f32_16x16x32_bf16((A), (B), (C), 0, 0, 0)

static __device__ __forceinline__ unsigned short f2bf(float f) {
    __bf16 b = (__bf16)f;
    return __builtin_bit_cast(unsigned short, b);
}
static __device__ __forceinline__ float bf2f(unsigned short s) {
    return __uint_as_float(((unsigned)s) << 16);
}
static __device__ __forceinline__ bf16x8 ldfrag(const unsigned short* p, int byte_off) {
    return *(const bf16x8*)((const char*)p + byte_off);
}

// NOTE (R10-R12 post-mortem): helpers MUST be macros, not lambdas. Lambda pointer
// params (float*, f32x4*) defeat SROA -> local arrays land in scratch (VGPR pinned
// 128, 284MB scratch writes, 6x slowdown). Macros keep compile-time-indexed arrays
// in registers (R6 precedent: LOAD_FC macro, 172 VGPR, no spill).

#define STAGE_X(BIDX, MLO, MHI)                                                 \
    do {                                                                        \
        const float* xb_ = x + (size_t)(BIDX) * NF;                             \
        _Pragma("unroll")                                                       \
        for (int it = 0; it < 5; ++it) {                                        \
            int e = lane + it * 64;                                             \
            if (e < NF) {                                                       \
                int n = e / 5, f = e - n * 5;                                   \
                float v = xb_[e];                                               \
                unsigned bit = (n < 32) ? (((MLO) >> n) & 1u)                   \
                                        : (((MHI) >> (n - 32)) & 1u);           \
                xsW0[n * XS_ST + f] = f2bf(v);                                  \
                xsW1[n * XS_ST + f] = f2bf(bit ? v : 0.0f);                     \
            }                                                                   \
        }                                                                       \
    } while (0)

#define LOAD_DSEL(DSEL, BB)                                                     \
    do {                                                                        \
        const float* dsp_ = (c < 5) ? s_dis1 : s_dis2[BB];                      \
        _Pragma("unroll")                                                       \
        for (int mt = 0; mt < 4; ++mt)                                          \
            _Pragma("unroll")                                                   \
            for (int i = 0; i < 4; ++i)                                         \
                DSEL[mt * 4 + i] = (c < 10) ? dsp_[mt * 16 + g * 4 + i] : 0.0f; \
    } while (0)

#define LOAD_XA(XA)                                                             \
    do {                                                                        \
        const unsigned short* xsp_ = (c >= 5 && c < 10) ? xsW1 : xsW0;          \
        _Pragma("unroll")                                                       \
        for (int mt = 0; mt < 4; ++mt)                                          \
            _Pragma("unroll")                                                   \
            for (int i = 0; i < 4; ++i)                                         \
                XA[mt][i] = (c < 10)                                            \
                    ? bf2f(xsp_[(mt * 16 + g * 4 + i) * XS_ST + f_c]) : 0.0f;   \
    } while (0)

#define PACK_U(DSEL, V)                                                         \
    do {                                                                        \
        if (c < 10) {                                                           \
            _Pragma("unroll")                                                   \
            for (int mt = 0; mt < 4; ++mt) {                                    \
                bf16x4 uv_;                                                     \
                uv_[0] = (__bf16)(DSEL[mt*4+0] * V[mt][0]);                     \
                uv_[1] = (__bf16)(DSEL[mt*4+1] * V[mt][1]);                     \
                uv_[2] = (__bf16)(DSEL[mt*4+2] * V[mt][2]);                     \
                uv_[3] = (__bf16)(DSEL[mt*4+3] * V[mt][3]);                     \
                *(bf16x4*)((char*)utW + c * U_BY + (mt * 16 + g * 4) * 2) = uv_;\
            }                                                                   \
        }                                                                       \
    } while (0)

// adj fragments re-read from LDS per step (keeps live VGPRs low; MFMA-latency path)
#define CHEB_STEP(K, DSEL, XA, X1F)                                             \
    do {                                                                        \
        const float cck_ = ((K) == 1) ? 1.0f : 2.0f;                            \
        bf16x8 Uf0_ = ldfrag(utW, c * U_BY + g * 16);                           \
        bf16x8 Uf1_ = ldfrag(utW, c * U_BY + 64 + g * 16);                      \
        _Pragma("unroll")                                                       \
        for (int mt = 0; mt < 4; ++mt) {                                        \
            bf16x8 adj0_ = ldfrag(s_adjb, (mt * 16 + c) * AD_BY + g * 16);      \
            bf16x8 adj1_ = ldfrag(s_adjb, (mt * 16 + c) * AD_BY + 64 + g * 16); \
            const f32x4 z_ = {0.f, 0.f, 0.f, 0.f};                              \
            f32x4 Ca_ = MFMA(adj0_, Uf0_, z_);                                  \
            f32x4 Cb_ = MFMA(adj1_, Uf1_, z_);                                  \
            f32x4 Cv_ = Ca_ + Cb_;                                              \
            f32x4 xn_;                                                          \
            _Pragma("unroll")                                                   \
            for (int i = 0; i < 4; ++i) {                                       \
                float vv_ = -cck_ * DSEL[mt * 4 + i] * Cv_[i];                  \
                if ((K) == 2) vv_ -= XA[mt][i];                                 \
                if ((K) == 3) vv_ -= X1F[mt][i];                                \
                xn_[i] = vv_;                                                   \
            }                                                                   \
            if (c < 10) {                                                       \
                unsigned short* dst_ = (c < 5) ? xsW0 : xsW1;                   \
                _Pragma("unroll")                                               \
                for (int i = 0; i < 4; ++i)                                     \
                    dst_[(mt * 16 + g * 4 + i) * XS_ST + (K) * 5 + f_c] = f2bf(xn_[i]); \
                if ((K) < 3) {                                                  \
                    bf16x4 uv_;                                                 \
                    uv_[0] = (__bf16)(DSEL[mt*4+0] * xn_[0]);                   \
                    uv_[1] = (__bf16)(DSEL[mt*4+1] * xn_[1]);                   \
                    uv_[2] = (__bf16)(DSEL[mt*4+2] * xn_[2]);                   \
                    uv_[3] = (__bf16)(DSEL[mt*4+3] * xn_[3]);                   \
                    *(bf16x4*)((char*)utW + c * U_BY + (mt * 16 + g * 4) * 2) = uv_; \
                }                                                               \
            }                                                                   \
            if ((K) == 1) X1F[mt] = xn_;                                        \
        }                                                                       \
    } while (0)

#define LOAD_AFRAGS(A1, A2)                                                     \
    do {                                                                        \
        _Pragma("unroll")                                                       \
        for (int mt = 0; mt < 4; ++mt) {                                        \
            A1[mt] = ldfrag(xsW0, (mt * 16 + c) * XS_BY + g * 16);              \
            A2[mt] = ldfrag(xsW1, (mt * 16 + c) * XS_BY + g * 16);              \
        }                                                                       \
    } while (0)

// branch-free epilogue group (rows 62/63: xs==0 exactly, fc rows zeroed)
#define EPI_GROUP(NT, A1, A2, AP)                                               \
    do {                                                                        \
        bf16x8 W1f_ = ldfrag(s_wt, (0 * 64 + (NT) * 16 + c) * WT_BY + g * 16);  \
        bf16x8 W2f_ = ldfrag(s_wt, (1 * 64 + (NT) * 16 + c) * WT_BY + g * 16);  \
        bf16x8 Wgf_ = ldfrag(s_wt, (2 * 64 + (NT) * 16 + c) * WT_BY + g * 16);  \
        const f32x2 bb12_ = { b1v[NT], b2v[NT] };                               \
        const float bbg_ = bgv[NT];                                             \
        _Pragma("unroll")                                                       \
        for (int mt = 0; mt < 4; ++mt) {                                        \
            const f32x4 z_ = {0.f, 0.f, 0.f, 0.f};                              \
            f32x4 C1_ = MFMA(A1[mt], W1f_, z_);                                 \
            f32x4 C2_ = MFMA(A2[mt], W2f_, z_);                                 \
            f32x4 Cg_ = MFMA(A1[mt], Wgf_, z_);                                 \
            _Pragma("unroll")                                                   \
            for (int i = 0; i < 4; ++i) {                                       \
                int r_ = mt * 16 + g * 4 + i;                                   \
                const u16x8 fcv_ = *(const u16x8*)((const char*)s_fc +          \
                                    ((r_ * CO + (NT) * 16 + c) << 4));          \
                f32x2 h12_ = f32x2{C1_[i], C2_[i]} + bb12_;                     \
                h12_.x = fmaxf(h12_.x, 0.f);                                    \
                h12_.y = fmaxf(h12_.y, 0.f);                                    \
                float hg_ = fmaxf(Cg_[i] + bbg_, 0.f);                          \
                AP[0] += f32x2{h12_.x, h12_.x} * f32x2{bf2f(fcv_[0]), bf2f(fcv_[1])}; \
                AP[1] += f32x2{h12_.x, h12_.y} * f32x2{bf2f(fcv_[2]), bf2f(fcv_[3])}; \
                AP[2] += f32x2{h12_.y, h12_.y} * f32x2{bf2f(fcv_[4]), bf2f(fcv_[5])}; \
                AP[3] += f32x2{hg_,    hg_   } * f32x2{bf2f(fcv_[6]), bf2f(fcv_[7])}; \
            }                                                                   \
        }                                                                       \
    } while (0)

__global__ __launch_bounds__(TPB, 1) void gnn_mfma(
    const float* __restrict__ x, const float* __restrict__ adj,
    const int* __restrict__ mask_idx,
    const float* __restrict__ gc_w, const float* __restrict__ gc_b,
    const float* __restrict__ gc1_w, const float* __restrict__ gc1_b,
    const float* __restrict__ gc2_w, const float* __restrict__ gc2_b,
    const float* __restrict__ fc1_w, const float* __restrict__ fc1_b,
    const float* __restrict__ fc2_w, const float* __restrict__ fc2_b,
    const float* __restrict__ cls_w, const float* __restrict__ cls_b,
    float* __restrict__ out)
{
    __shared__ __align__(16) unsigned short s_adjb[64 * AD_ST];      // 9216 B
    __shared__ __align__(16) unsigned short s_wt[3 * 64 * 40];       // 15360 B
    __shared__ __align__(16) unsigned short s_fc[64 * CO * 8];       // 65536 B, rows 62/63 zero
    __shared__ float s_bias[3][64];                                  // 768 B
    __shared__ float s_dis1[64];                                     // 256 B
    __shared__ float s_dis2[BPB][64];                                // 4096 B
    __shared__ unsigned s_mb[BPB][2];                                // 128 B
    __shared__ __align__(16) unsigned short s_ut[8][16 * AD_ST];     // 18432 B per-wave U^T
    __shared__ __align__(16) unsigned short s_xs[8 * 2 * 64 * XS_ST + 8]; // 49168 B
    // total 162960 B <= 163840

    const int t = threadIdx.x;
    const int w = t >> 6, lane = t & 63;
    const int g = lane >> 4, c = lane & 15;
    const int b0 = blockIdx.x * BPB;

    // ================= block-cooperative staging =================
    for (int i = t; i < 64 * AD_ST; i += TPB) {
        int r = i / AD_ST, cc = i - r * AD_ST;
        float v = (r < NN && cc < NN) ? adj[r * NN + cc] : 0.0f;
        s_adjb[i] = f2bf(v);
    }
    for (int i = t; i < 3 * 64 * 40; i += TPB) {
        int head = i / 2560, rem = i - head * 2560;
        int o = rem / 40, kf = rem - o * 40;
        const float* wp = (head == 0) ? gc1_w : (head == 1) ? gc2_w : gc_w;
        s_wt[i] = f2bf((kf < KC * FF) ? wp[kf * CO + o] : 0.0f);
    }
    for (int i = t; i < 64 * CO; i += TPB) {
        int r = i >> 6;
        u16x8 v;
        if (r < NN) {
            const float* f1p = fc1_w + i * 3;
            const float* f2p = fc2_w + i * 3;
            const float* fgp = cls_w + i * 2;
            v[0] = f2bf(f1p[0]); v[1] = f2bf(f1p[1]); v[2] = f2bf(f1p[2]);
            v[3] = f2bf(f2p[0]); v[4] = f2bf(f2p[1]); v[5] = f2bf(f2p[2]);
            v[6] = f2bf(fgp[0]); v[7] = f2bf(fgp[1]);
        } else {
            #pragma unroll
            for (int j = 0; j < 8; ++j) v[j] = (unsigned short)0;
        }
        *(u16x8*)&s_fc[i * 8] = v;
    }
    if (t < 192) {
        int head = t >> 6, o = t & 63;
        const float* bp = (head == 0) ? gc1_b : (head == 1) ? gc2_b : gc_b;
        s_bias[head][o] = bp[o];
    }
    if (t < BPB * 2) ((unsigned*)s_mb)[t] = 0u;
    if (t < 8) s_xs[8 * 2 * 64 * XS_ST + t] = 0;
    __syncthreads();   // B1

    for (int i = t; i < BPB * NSEL; i += TPB) {
        int bt = i / NSEL, s = i - bt * NSEL;
        int idx = mask_idx[(b0 + bt) * NSEL + s];
        atomicOr(&s_mb[bt][idx >> 5], 1u << (idx & 31));
    }
    __syncthreads();   // B2

    // ---- dis1/dis2 via MFMA on staged bf16 adj ----
    if (w < 4) {
        unsigned mlo = s_mb[c][0], mhi = s_mb[c][1];
        bf16x8 M0, M1;
        #pragma unroll
        for (int e = 0; e < 8; ++e) {
            int l = g * 8 + e;
            M0[e] = __builtin_bit_cast(__bf16, (unsigned short)(((mlo >> l) & 1u) ? 0x3F80 : 0));
            M1[e] = __builtin_bit_cast(__bf16, (unsigned short)(((mhi >> l) & 1u) ? 0x3F80 : 0));
        }
        bf16x8 A0 = ldfrag(s_adjb, (w * 16 + c) * AD_BY + g * 16);
        bf16x8 A1 = ldfrag(s_adjb, (w * 16 + c) * AD_BY + 64 + g * 16);
        f32x4 Cd = {0.f, 0.f, 0.f, 0.f};
        Cd = MFMA(A0, M0, Cd);
        Cd = MFMA(A1, M1, Cd);
        #pragma unroll
        for (int i = 0; i < 4; ++i) {
            int j = w * 16 + g * 4 + i;
            unsigned bit = (j < 32) ? ((mlo >> j) & 1u) : ((mhi >> (j - 32)) & 1u);
            float s = bit ? Cd[i] : 0.0f;
            s_dis2[c][j] = (s > 0.0f) ? rsqrtf(s) : 0.0f;
        }
    } else if (w == 4) {
        bf16x8 ones;
        #pragma unroll
        for (int e = 0; e < 8; ++e)
            ones[e] = __builtin_bit_cast(__bf16, (unsigned short)0x3F80);
        #pragma unroll
        for (int mt = 0; mt < 4; ++mt) {
            bf16x8 A0 = ldfrag(s_adjb, (mt * 16 + c) * AD_BY + g * 16);
            bf16x8 A1 = ldfrag(s_adjb, (mt * 16 + c) * AD_BY + 64 + g * 16);
            f32x4 Cd = {0.f, 0.f, 0.f, 0.f};
            Cd = MFMA(A0, ones, Cd);
            Cd = MFMA(A1, ones, Cd);
            if (c == 0) {
                #pragma unroll
                for (int i = 0; i < 4; ++i) {
                    float d = Cd[i];
                    s_dis1[mt * 16 + g * 4 + i] = (d > 0.0f) ? rsqrtf(d) : 0.0f;
                }
            }
        }
    }
    __syncthreads();   // B3 -- last barrier

    // ================= wave-private =================
    unsigned short* xsW0 = &s_xs[(w * 2 + 0) * 64 * XS_ST];
    unsigned short* xsW1 = &s_xs[(w * 2 + 1) * 64 * XS_ST];
    unsigned short* utW  = &s_ut[w][0];
    {
        unsigned* z = (unsigned*)xsW0;
        for (int i = lane; i < 64 * XS_ST; i += 64) z[i] = 0u;
        unsigned* zu = (unsigned*)utW;
        for (int i = lane; i < 16 * AD_ST / 2; i += 64) zu[i] = 0u;
    }

    float b1v[4], b2v[4], bgv[4];
    #pragma unroll
    for (int nt = 0; nt < 4; ++nt) {
        b1v[nt] = s_bias[0][nt * 16 + c];
        b2v[nt] = s_bias[1][nt * 16 + c];
        bgv[nt] = s_bias[2][nt * 16 + c];
    }

    const int f_c = (c < 5) ? c : (c < 10 ? c - 5 : 0);
    const int bb0 = w * 2, bb1 = w * 2 + 1;
    const unsigned mlo0 = s_mb[bb0][0], mhi0 = s_mb[bb0][1];
    const unsigned mlo1 = s_mb[bb1][0], mhi1 = s_mb[bb1][1];

    f32x2 acc0[4], acc1[4];
    #pragma unroll
    for (int q = 0; q < 4; ++q) { acc0[q] = f32x2{0.f, 0.f}; acc1[q] = f32x2{0.f, 0.f}; }

    float dsel0[16], dsel1[16];
    f32x4 xA0[4], x1f0[4], xA1[4], x1f1[4];
    bf16x8 A1f0[4], A2f0[4], A1f1[4], A2f1[4];

    // ---- batch 0: full cheb, A-frags ----
    STAGE_X(b0 + bb0, mlo0, mhi0);
    LOAD_DSEL(dsel0, bb0);
    LOAD_XA(xA0);
    PACK_U(dsel0, xA0);
    CHEB_STEP(1, dsel0, xA0, x1f0);
    CHEB_STEP(2, dsel0, xA0, x1f0);
    CHEB_STEP(3, dsel0, xA0, x1f0);
    LOAD_AFRAGS(A1f0, A2f0);

    // ---- batch 1 prep (xs overwrite OK: b0 frags in regs) ----
    STAGE_X(b0 + bb1, mlo1, mhi1);
    LOAD_DSEL(dsel1, bb1);
    LOAD_XA(xA1);
    PACK_U(dsel1, xA1);

    // ---- software pipeline: cheb(b1) k-steps interleaved with epilogue(b0) ----
    CHEB_STEP(1, dsel1, xA1, x1f1);
    EPI_GROUP(0, A1f0, A2f0, acc0);
    CHEB_STEP(2, dsel1, xA1, x1f1);
    EPI_GROUP(1, A1f0, A2f0, acc0);
    CHEB_STEP(3, dsel1, xA1, x1f1);
    EPI_GROUP(2, A1f0, A2f0, acc0);
    LOAD_AFRAGS(A1f1, A2f1);
    EPI_GROUP(3, A1f0, A2f0, acc0);
    EPI_GROUP(0, A1f1, A2f1, acc1);
    EPI_GROUP(1, A1f1, A2f1, acc1);
    EPI_GROUP(2, A1f1, A2f1, acc1);
    EPI_GROUP(3, A1f1, A2f1, acc1);

    // ---- wave reduction + output ----
    float red[16] = {
        acc0[0].x, acc0[0].y, acc0[1].x, acc0[1].y,
        acc0[2].x, acc0[2].y, acc0[3].x, acc0[3].y,
        acc1[0].x, acc1[0].y, acc1[1].x, acc1[1].y,
        acc1[2].x, acc1[2].y, acc1[3].x, acc1[3].y
    };
    #pragma unroll
    for (int off = 32; off > 0; off >>= 1)
        #pragma unroll
        for (int q = 0; q < 16; ++q)
            red[q] += __shfl_down(red[q], off);

    if (lane == 0) {
        #pragma unroll
        for (int bi = 0; bi < 2; ++bi) {
            const int b = b0 + w * 2 + bi;
            const float* r = &red[bi * 8];
            float l0 = r[0] + fc1_b[0];
            float l1 = r[1] + fc1_b[1];
            float l2 = r[2] + fc1_b[2];
            float m0 = r[3] + fc2_b[0];
            float m1 = r[4] + fc2_b[1];
            float m2 = r[5] + fc2_b[2];
            float g0 = r[6] + cls_b[0];
            float g1 = r[7] + cls_b[1];
            float mx = fmaxf(g0, g1);
            float e0 = expf(g0 - mx), e1 = expf(g1 - mx);
            float inv = 1.0f / (e0 + e1);
            float p0 = e0 * inv, p1 = e1 * inv;
            out[b * 3 + 0] = l0 * p0 + m0 * p1;
            out[b * 3 + 1] = l1 * p0 + m1 * p1;
            out[b * 3 + 2] = l2 * p0 + m2 * p1;
        }
    }
}

extern "C" void kernel_launch(void* const* d_in, const int* in_sizes, int n_in,
                              void* d_out, int out_size, void* d_ws, size_t ws_size,
                              hipStream_t stream) {
    const float* x      = (const float*)d_in[0];
    const float* adj    = (const float*)d_in[1];
    const int*   midx   = (const int*)  d_in[2];
    const float* gc_w   = (const float*)d_in[3];
    const float* gc_b   = (const float*)d_in[4];
    const float* gc1_w  = (const float*)d_in[5];
    const float* gc1_b  = (const float*)d_in[6];
    const float* gc2_w  = (const float*)d_in[7];
    const float* gc2_b  = (const float*)d_in[8];
    const float* fc1_w  = (const float*)d_in[9];
    const float* fc1_b  = (const float*)d_in[10];
    const float* fc2_w  = (const float*)d_in[11];
    const float* fc2_b  = (const float*)d_in[12];
    const float* cls_w  = (const float*)d_in[13];
    const float* cls_b  = (const float*)d_in[14];
    float* o = (float*)d_out;
    hipLaunchKernelGGL(gnn_mfma, dim3(NBATCH / BPB), dim3(TPB), 0, stream,
        x, adj, midx, gc_w, gc_b, gc1_w, gc1_b, gc2_w, gc2_b,
        fc1_w, fc1_b, fc2_w, fc2_b, cls_w, cls_b, o);
}

// Round 14
// 72.166 us; speedup vs baseline: 2.6085x; 1.0260x over previous
//
#include <hip/hip_runtime.h>

#define NN 62
#define FF 5
#define KC 4
#define CO 64
#define NSEL 31
#define NF 310
#define NBATCH 4096
#define TPB 512        // 8 waves, 2/SIMD, one block/CU
#define BPB 16         // 8 waves x 2 batches
#define XS_ST 24       // xs row stride elems
#define XS_BY 48
#define AD_ST 72
#define AD_BY 144
#define WT_BY 80
#define U_BY  144

typedef __bf16 bf16x8 __attribute__((ext_vector_type(8)));
typedef __bf16 bf16x4 __attribute__((ext_vector_type(4)));
typedef float f32x4 __attribute__((ext_vector_type(4)));
typedef float f32x2 __attribute__((ext_vector_type(2)));
typedef unsigned short u16x8 __attribute__((ext_vector_type(8)));

#define MFMA(A, B, C) __builtin_amdgcn_mfma_f32_16x16x32_bf16((A), (B), (C), 0, 0, 0)

static __device__ __forceinline__ unsigned short f2bf(float f) {
    __bf16 b = (__bf16)f;
    return __builtin_bit_cast(unsigned short, b);
}
static __device__ __forceinline__ float bf2f(unsigned short s) {
    return __uint_as_float(((unsigned)s) << 16);
}
static __device__ __forceinline__ bf16x8 ldfrag(const unsigned short* p, int byte_off) {
    return *(const bf16x8*)((const char*)p + byte_off);
}

// R10-R13 lesson: TPB=512 kernels are hard-capped at 128 VGPRs by this toolchain
// (all launch_bounds variants). So ALL pipeline state that can live in LDS must:
// dis/bias/x0/x1 are re-read from LDS inside the step macros; only A-frags (32)
// + acc (16) persist in registers. Helpers are macros (lambdas defeat SROA).

#define STAGE_X(BIDX, MLO, MHI)                                                 \
    do {                                                                        \
        const float* xb_ = x + (size_t)(BIDX) * NF;                             \
        _Pragma("unroll")                                                       \
        for (int it = 0; it < 5; ++it) {                                        \
            int e = lane + it * 64;                                             \
            if (e < NF) {                                                       \
                int n = e / 5, f = e - n * 5;                                   \
                float v = xb_[e];                                               \
                unsigned bit = (n < 32) ? (((MLO) >> n) & 1u)                   \
                                        : (((MHI) >> (n - 32)) & 1u);           \
                xsW0[n * XS_ST + f] = f2bf(v);                                  \
                xsW1[n * XS_ST + f] = f2bf(bit ? v : 0.0f);                     \
            }                                                                   \
        }                                                                       \
    } while (0)

// U0 = dis .* x0, all operands read from LDS (no persistent registers)
#define PACK_U0(BB)                                                             \
    do {                                                                        \
        if (c < 10) {                                                           \
            const unsigned short* xsp_ = (c >= 5) ? xsW1 : xsW0;                \
            const float* dsp_ = (c < 5) ? s_dis1 : s_dis2[BB];                  \
            _Pragma("unroll")                                                   \
            for (int mt = 0; mt < 4; ++mt) {                                    \
                bf16x4 uv_;                                                     \
                _Pragma("unroll")                                               \
                for (int i = 0; i < 4; ++i) {                                   \
                    int r_ = mt * 16 + g * 4 + i;                               \
                    uv_[i] = (__bf16)(dsp_[r_] * bf2f(xsp_[r_ * XS_ST + f_c])); \
                }                                                               \
                *(bf16x4*)((char*)utW + c * U_BY + (mt * 16 + g * 4) * 2) = uv_;\
            }                                                                   \
        }                                                                       \
    } while (0)

// cheb step K: adj frags + dis + x_{k-2} all re-read from LDS (transient regs only)
#define CHEB_STEP(K, BB)                                                        \
    do {                                                                        \
        const float cck_ = ((K) == 1) ? 1.0f : 2.0f;                            \
        bf16x8 Uf0_ = ldfrag(utW, c * U_BY + g * 16);                           \
        bf16x8 Uf1_ = ldfrag(utW, c * U_BY + 64 + g * 16);                      \
        const unsigned short* xsp_ = (c >= 5 && c < 10) ? xsW1 : xsW0;          \
        const float* dsp_ = (c < 5) ? s_dis1 : s_dis2[BB];                      \
        _Pragma("unroll")                                                       \
        for (int mt = 0; mt < 4; ++mt) {                                        \
            bf16x8 adj0_ = ldfrag(s_adjb, (mt * 16 + c) * AD_BY + g * 16);      \
            bf16x8 adj1_ = ldfrag(s_adjb, (mt * 16 + c) * AD_BY + 64 + g * 16); \
            const f32x4 z_ = {0.f, 0.f, 0.f, 0.f};                              \
            f32x4 Ca_ = MFMA(adj0_, Uf0_, z_);                                  \
            f32x4 Cb_ = MFMA(adj1_, Uf1_, z_);                                  \
            f32x4 Cv_ = Ca_ + Cb_;                                              \
            if (c < 10) {                                                       \
                unsigned short* dst_ = (c < 5) ? xsW0 : xsW1;                   \
                bf16x4 uv_;                                                     \
                _Pragma("unroll")                                               \
                for (int i = 0; i < 4; ++i) {                                   \
                    int r_ = mt * 16 + g * 4 + i;                               \
                    float vv_ = -cck_ * dsp_[r_] * Cv_[i];                      \
                    if ((K) == 2) vv_ -= bf2f(xsp_[r_ * XS_ST + f_c]);          \
                    if ((K) == 3) vv_ -= bf2f(xsp_[r_ * XS_ST + 5 + f_c]);      \
                    dst_[r_ * XS_ST + (K) * 5 + f_c] = f2bf(vv_);               \
                    uv_[i] = (__bf16)(dsp_[r_] * vv_);                          \
                }                                                               \
                if ((K) < 3)                                                    \
                    *(bf16x4*)((char*)utW + c * U_BY + (mt * 16 + g * 4) * 2) = uv_; \
            }                                                                   \
        }                                                                       \
    } while (0)

#define LOAD_AFRAGS(A1, A2)                                                     \
    do {                                                                        \
        _Pragma("unroll")                                                       \
        for (int mt = 0; mt < 4; ++mt) {                                        \
            A1[mt] = ldfrag(xsW0, (mt * 16 + c) * XS_BY + g * 16);              \
            A2[mt] = ldfrag(xsW1, (mt * 16 + c) * XS_BY + g * 16);              \
        }                                                                       \
    } while (0)

// branch-free epilogue group; bias read from LDS inline (no persistent regs)
#define EPI_GROUP(NT, A1, A2, AP)                                               \
    do {                                                                        \
        bf16x8 W1f_ = ldfrag(s_wt, (0 * 64 + (NT) * 16 + c) * WT_BY + g * 16);  \
        bf16x8 W2f_ = ldfrag(s_wt, (1 * 64 + (NT) * 16 + c) * WT_BY + g * 16);  \
        bf16x8 Wgf_ = ldfrag(s_wt, (2 * 64 + (NT) * 16 + c) * WT_BY + g * 16);  \
        const f32x2 bb12_ = { s_bias[0][(NT) * 16 + c], s_bias[1][(NT) * 16 + c] }; \
        const float bbg_ = s_bias[2][(NT) * 16 + c];                            \
        _Pragma("unroll")                                                       \
        for (int mt = 0; mt < 4; ++mt) {                                        \
            const f32x4 z_ = {0.f, 0.f, 0.f, 0.f};                              \
            f32x4 C1_ = MFMA(A1[mt], W1f_, z_);                                 \
            f32x4 C2_ = MFMA(A2[mt], W2f_, z_);                                 \
            f32x4 Cg_ = MFMA(A1[mt], Wgf_, z_);                                 \
            _Pragma("unroll")                                                   \
            for (int i = 0; i < 4; ++i) {                                       \
                int r_ = mt * 16 + g * 4 + i;                                   \
                const u16x8 fcv_ = *(const u16x8*)((const char*)s_fc +          \
                                    ((r_ * CO + (NT) * 16 + c) << 4));          \
                f32x2 h12_ = f32x2{C1_[i], C2_[i]} + bb12_;                     \
                h12_.x = fmaxf(h12_.x, 0.f);                                    \
                h12_.y = fmaxf(h12_.y, 0.f);                                    \
                float hg_ = fmaxf(Cg_[i] + bbg_, 0.f);                          \
                AP[0] += f32x2{h12_.x, h12_.x} * f32x2{bf2f(fcv_[0]), bf2f(fcv_[1])}; \
                AP[1] += f32x2{h12_.x, h12_.y} * f32x2{bf2f(fcv_[2]), bf2f(fcv_[3])}; \
                AP[2] += f32x2{h12_.y, h12_.y} * f32x2{bf2f(fcv_[4]), bf2f(fcv_[5])}; \
                AP[3] += f32x2{hg_,    hg_   } * f32x2{bf2f(fcv_[6]), bf2f(fcv_[7])}; \
            }                                                                   \
        }                                                                       \
    } while (0)

__global__ __launch_bounds__(TPB) void gnn_mfma(
    const float* __restrict__ x, const float* __restrict__ adj,
    const int* __restrict__ mask_idx,
    const float* __restrict__ gc_w, const float* __restrict__ gc_b,
    const float* __restrict__ gc1_w, const float* __restrict__ gc1_b,
    const float* __restrict__ gc2_w, const float* __restrict__ gc2_b,
    const float* __restrict__ fc1_w, const float* __restrict__ fc1_b,
    const float* __restrict__ fc2_w, const float* __restrict__ fc2_b,
    const float* __restrict__ cls_w, const float* __restrict__ cls_b,
    float* __restrict__ out)
{
    __shared__ __align__(16) unsigned short s_adjb[64 * AD_ST];      // 9216 B
    __shared__ __align__(16) unsigned short s_wt[3 * 64 * 40];       // 15360 B
    __shared__ __align__(16) unsigned short s_fc[64 * CO * 8];       // 65536 B, rows 62/63 zero
    __shared__ float s_bias[3][64];                                  // 768 B
    __shared__ float s_dis1[64];                                     // 256 B
    __shared__ float s_dis2[BPB][64];                                // 4096 B
    __shared__ unsigned s_mb[BPB][2];                                // 128 B
    __shared__ __align__(16) unsigned short s_ut[8][16 * AD_ST];     // 18432 B per-wave U^T
    __shared__ __align__(16) unsigned short s_xs[8 * 2 * 64 * XS_ST + 8]; // 49168 B
    // total 162960 B <= 163840

    const int t = threadIdx.x;
    const int w = t >> 6, lane = t & 63;
    const int g = lane >> 4, c = lane & 15;
    const int b0 = blockIdx.x * BPB;

    // ================= block-cooperative staging =================
    for (int i = t; i < 64 * AD_ST; i += TPB) {
        int r = i / AD_ST, cc = i - r * AD_ST;
        float v = (r < NN && cc < NN) ? adj[r * NN + cc] : 0.0f;
        s_adjb[i] = f2bf(v);
    }
    for (int i = t; i < 3 * 64 * 40; i += TPB) {
        int head = i / 2560, rem = i - head * 2560;
        int o = rem / 40, kf = rem - o * 40;
        const float* wp = (head == 0) ? gc1_w : (head == 1) ? gc2_w : gc_w;
        s_wt[i] = f2bf((kf < KC * FF) ? wp[kf * CO + o] : 0.0f);
    }
    for (int i = t; i < 64 * CO; i += TPB) {
        int r = i >> 6;
        u16x8 v;
        if (r < NN) {
            const float* f1p = fc1_w + i * 3;
            const float* f2p = fc2_w + i * 3;
            const float* fgp = cls_w + i * 2;
            v[0] = f2bf(f1p[0]); v[1] = f2bf(f1p[1]); v[2] = f2bf(f1p[2]);
            v[3] = f2bf(f2p[0]); v[4] = f2bf(f2p[1]); v[5] = f2bf(f2p[2]);
            v[6] = f2bf(fgp[0]); v[7] = f2bf(fgp[1]);
        } else {
            #pragma unroll
            for (int j = 0; j < 8; ++j) v[j] = (unsigned short)0;
        }
        *(u16x8*)&s_fc[i * 8] = v;
    }
    if (t < 192) {
        int head = t >> 6, o = t & 63;
        const float* bp = (head == 0) ? gc1_b : (head == 1) ? gc2_b : gc_b;
        s_bias[head][o] = bp[o];
    }
    if (t < BPB * 2) ((unsigned*)s_mb)[t] = 0u;
    if (t < 8) s_xs[8 * 2 * 64 * XS_ST + t] = 0;
    __syncthreads();   // B1

    for (int i = t; i < BPB * NSEL; i += TPB) {
        int bt = i / NSEL, s = i - bt * NSEL;
        int idx = mask_idx[(b0 + bt) * NSEL + s];
        atomicOr(&s_mb[bt][idx >> 5], 1u << (idx & 31));
    }
    __syncthreads();   // B2

    // ---- dis1/dis2 via MFMA on staged bf16 adj ----
    if (w < 4) {
        unsigned mlo = s_mb[c][0], mhi = s_mb[c][1];
        bf16x8 M0, M1;
        #pragma unroll
        for (int e = 0; e < 8; ++e) {
            int l = g * 8 + e;
            M0[e] = __builtin_bit_cast(__bf16, (unsigned short)(((mlo >> l) & 1u) ? 0x3F80 : 0));
            M1[e] = __builtin_bit_cast(__bf16, (unsigned short)(((mhi >> l) & 1u) ? 0x3F80 : 0));
        }
        bf16x8 A0 = ldfrag(s_adjb, (w * 16 + c) * AD_BY + g * 16);
        bf16x8 A1 = ldfrag(s_adjb, (w * 16 + c) * AD_BY + 64 + g * 16);
        f32x4 Cd = {0.f, 0.f, 0.f, 0.f};
        Cd = MFMA(A0, M0, Cd);
        Cd = MFMA(A1, M1, Cd);
        #pragma unroll
        for (int i = 0; i < 4; ++i) {
            int j = w * 16 + g * 4 + i;
            unsigned bit = (j < 32) ? ((mlo >> j) & 1u) : ((mhi >> (j - 32)) & 1u);
            float s = bit ? Cd[i] : 0.0f;
            s_dis2[c][j] = (s > 0.0f) ? rsqrtf(s) : 0.0f;
        }
    } else if (w == 4) {
        bf16x8 ones;
        #pragma unroll
        for (int e = 0; e < 8; ++e)
            ones[e] = __builtin_bit_cast(__bf16, (unsigned short)0x3F80);
        #pragma unroll
        for (int mt = 0; mt < 4; ++mt) {
            bf16x8 A0 = ldfrag(s_adjb, (mt * 16 + c) * AD_BY + g * 16);
            bf16x8 A1 = ldfrag(s_adjb, (mt * 16 + c) * AD_BY + 64 + g * 16);
            f32x4 Cd = {0.f, 0.f, 0.f, 0.f};
            Cd = MFMA(A0, ones, Cd);
            Cd = MFMA(A1, ones, Cd);
            if (c == 0) {
                #pragma unroll
                for (int i = 0; i < 4; ++i) {
                    float d = Cd[i];
                    s_dis1[mt * 16 + g * 4 + i] = (d > 0.0f) ? rsqrtf(d) : 0.0f;
                }
            }
        }
    }
    __syncthreads();   // B3 -- last barrier

    // ================= wave-private =================
    unsigned short* xsW0 = &s_xs[(w * 2 + 0) * 64 * XS_ST];
    unsigned short* xsW1 = &s_xs[(w * 2 + 1) * 64 * XS_ST];
    unsigned short* utW  = &s_ut[w][0];
    {
        unsigned* z = (unsigned*)xsW0;
        for (int i = lane; i < 64 * XS_ST; i += 64) z[i] = 0u;
        unsigned* zu = (unsigned*)utW;
        for (int i = lane; i < 16 * AD_ST / 2; i += 64) zu[i] = 0u;
    }

    const int f_c = (c < 5) ? c : (c < 10 ? c - 5 : 0);
    const int bb0 = w * 2, bb1 = w * 2 + 1;
    const unsigned mlo0 = s_mb[bb0][0], mhi0 = s_mb[bb0][1];
    const unsigned mlo1 = s_mb[bb1][0], mhi1 = s_mb[bb1][1];

    f32x2 acc0[4], acc1[4];
    #pragma unroll
    for (int q = 0; q < 4; ++q) { acc0[q] = f32x2{0.f, 0.f}; acc1[q] = f32x2{0.f, 0.f}; }

    bf16x8 A1f0[4], A2f0[4], A1f1[4], A2f1[4];

    // ---- batch 0: full cheb (all state in LDS), A-frags ----
    STAGE_X(b0 + bb0, mlo0, mhi0);
    PACK_U0(bb0);
    CHEB_STEP(1, bb0);
    CHEB_STEP(2, bb0);
    CHEB_STEP(3, bb0);
    LOAD_AFRAGS(A1f0, A2f0);

    // ---- batch 1 prep (xs overwrite OK: b0 frags in regs) ----
    STAGE_X(b0 + bb1, mlo1, mhi1);
    PACK_U0(bb1);

    // ---- software pipeline: cheb(b1) interleaved with epilogue(b0) ----
    CHEB_STEP(1, bb1);
    EPI_GROUP(0, A1f0, A2f0, acc0);
    CHEB_STEP(2, bb1);
    EPI_GROUP(1, A1f0, A2f0, acc0);
    CHEB_STEP(3, bb1);
    EPI_GROUP(2, A1f0, A2f0, acc0);
    EPI_GROUP(3, A1f0, A2f0, acc0);   // b0 frags die here (peak frag-live = 32)
    LOAD_AFRAGS(A1f1, A2f1);
    EPI_GROUP(0, A1f1, A2f1, acc1);
    EPI_GROUP(1, A1f1, A2f1, acc1);
    EPI_GROUP(2, A1f1, A2f1, acc1);
    EPI_GROUP(3, A1f1, A2f1, acc1);

    // ---- wave reduction + output ----
    float red[16] = {
        acc0[0].x, acc0[0].y, acc0[1].x, acc0[1].y,
        acc0[2].x, acc0[2].y, acc0[3].x, acc0[3].y,
        acc1[0].x, acc1[0].y, acc1[1].x, acc1[1].y,
        acc1[2].x, acc1[2].y, acc1[3].x, acc1[3].y
    };
    #pragma unroll
    for (int off = 32; off > 0; off >>= 1)
        #pragma unroll
        for (int q = 0; q < 16; ++q)
            red[q] += __shfl_down(red[q], off);

    if (lane == 0) {
        #pragma unroll
        for (int bi = 0; bi < 2; ++bi) {
            const int b = b0 + w * 2 + bi;
            const float* r = &red[bi * 8];
            float l0 = r[0] + fc1_b[0];
            float l1 = r[1] + fc1_b[1];
            float l2 = r[2] + fc1_b[2];
            float m0 = r[3] + fc2_b[0];
            float m1 = r[4] + fc2_b[1];
            float m2 = r[5] + fc2_b[2];
            float g0 = r[6] + cls_b[0];
            float g1 = r[7] + cls_b[1];
            float mx = fmaxf(g0, g1);
            float e0 = expf(g0 - mx), e1 = expf(g1 - mx);
            float inv = 1.0f / (e0 + e1);
            float p0 = e0 * inv, p1 = e1 * inv;
            out[b * 3 + 0] = l0 * p0 + m0 * p1;
            out[b * 3 + 1] = l1 * p0 + m1 * p1;
            out[b * 3 + 2] = l2 * p0 + m2 * p1;
        }
    }
}

extern "C" void kernel_launch(void* const* d_in, const int* in_sizes, int n_in,
                              void* d_out, int out_size, void* d_ws, size_t ws_size,
                              hipStream_t stream) {
    const float* x      = (const float*)d_in[0];
    const float* adj    = (const float*)d_in[1];
    const int*   midx   = (const int*)  d_in[2];
    const float* gc_w   = (const float*)d_in[3];
    const float* gc_b   = (const float*)d_in[4];
    const float* gc1_w  = (const float*)d_in[5];
    const float* gc1_b  = (const float*)d_in[6];
    const float* gc2_w  = (const float*)d_in[7];
    const float* gc2_b  = (const float*)d_in[8];
    const float* fc1_w  = (const float*)d_in[9];
    const float* fc1_b  = (const float*)d_in[10];
    const float* fc2_w  = (const float*)d_in[11];
    const float* fc2_b  = (const float*)d_in[12];
    const float* cls_w  = (const float*)d_in[13];
    const float* cls_b  = (const float*)d_in[14];
    float* o = (float*)d_out;
    hipLaunchKernelGGL(gnn_mfma, dim3(NBATCH / BPB), dim3(TPB), 0, stream,
        x, adj, midx, gc_w, gc_b, gc1_w, gc1_b, gc2_w, gc2_b,
        fc1_w, fc1_b, fc2_w, fc2_b, cls_w, cls_b, o);
}

// Round 15
// 31.018 us; speedup vs baseline: 6.0688x; 2.3266x over previous
//
#include <hip/hip_runtime.h>

#define NN 62
#define FF 5
#define KC 4
#define CO 64
#define NSEL 31
#define NF 310
#define NBATCH 4096
#define TPB 512        // 8 waves, 2/SIMD, one block/CU
#define BPB 16         // 8 waves x 2 batches
#define XS_ST 24       // xs row stride elems
#define XS_BY 48
#define AD_ST 72
#define AD_BY 144
#define WT_BY 80
#define U_BY  144

typedef __bf16 bf16x8 __attribute__((ext_vector_type(8)));
typedef __bf16 bf16x4 __attribute__((ext_vector_type(4)));
typedef float f32x4 __attribute__((ext_vector_type(4)));
typedef float f32x2 __attribute__((ext_vector_type(2)));
typedef unsigned short u16x8 __attribute__((ext_vector_type(8)));

#define MFMA(A, B, C) __builtin_amdgcn_mfma_f32_16x16x32_bf16((A), (B), (C), 0, 0, 0)

static __device__ __forceinline__ unsigned short f2bf(float f) {
    __bf16 b = (__bf16)f;
    return __builtin_bit_cast(unsigned short, b);
}
static __device__ __forceinline__ float bf2f(unsigned short s) {
    return __uint_as_float(((unsigned)s) << 16);
}
static __device__ __forceinline__ bf16x8 ldfrag(const unsigned short* p, int byte_off) {
    return *(const bf16x8*)((const char*)p + byte_off);
}

// R10-R14 lesson: the interleaved cheb||epilogue schedule spills at TPB=512
// (scheduler hoists loads across the block; VGPR hard-capped at 128). The
// sequential R9 schedule allocates 124 VGPR with zero scratch. This kernel is
// R9's skeleton + f32x2 packed epilogue tail + independent cheb MFMA pairs.

__global__ __launch_bounds__(TPB) void gnn_mfma(
    const float* __restrict__ x, const float* __restrict__ adj,
    const int* __restrict__ mask_idx,
    const float* __restrict__ gc_w, const float* __restrict__ gc_b,
    const float* __restrict__ gc1_w, const float* __restrict__ gc1_b,
    const float* __restrict__ gc2_w, const float* __restrict__ gc2_b,
    const float* __restrict__ fc1_w, const float* __restrict__ fc1_b,
    const float* __restrict__ fc2_w, const float* __restrict__ fc2_b,
    const float* __restrict__ cls_w, const float* __restrict__ cls_b,
    float* __restrict__ out)
{
    __shared__ __align__(16) unsigned short s_adjb[64 * AD_ST];      // 9216 B
    __shared__ __align__(16) unsigned short s_wt[3 * 64 * 40];       // 15360 B
    __shared__ __align__(16) unsigned short s_fc[64 * CO * 8];       // 65536 B, rows 62/63 zero
    __shared__ float s_bias[3][64];                                  // 768 B
    __shared__ float s_dis1[64];                                     // 256 B
    __shared__ float s_dis2[BPB][64];                                // 4096 B
    __shared__ unsigned s_mb[BPB][2];                                // 128 B
    __shared__ __align__(16) unsigned short s_ut[8][16 * AD_ST];     // 18432 B per-wave U^T
    __shared__ __align__(16) unsigned short s_xs[8 * 2 * 64 * XS_ST + 8]; // 49168 B
    // total 162960 B <= 163840

    const int t = threadIdx.x;
    const int w = t >> 6, lane = t & 63;
    const int g = lane >> 4, c = lane & 15;
    const int b0 = blockIdx.x * BPB;

    // ================= block-cooperative staging =================
    for (int i = t; i < 64 * AD_ST; i += TPB) {
        int r = i / AD_ST, cc = i - r * AD_ST;
        float v = (r < NN && cc < NN) ? adj[r * NN + cc] : 0.0f;
        s_adjb[i] = f2bf(v);
    }
    for (int i = t; i < 3 * 64 * 40; i += TPB) {
        int head = i / 2560, rem = i - head * 2560;
        int o = rem / 40, kf = rem - o * 40;
        const float* wp = (head == 0) ? gc1_w : (head == 1) ? gc2_w : gc_w;
        s_wt[i] = f2bf((kf < KC * FF) ? wp[kf * CO + o] : 0.0f);
    }
    for (int i = t; i < 64 * CO; i += TPB) {
        int r = i >> 6;
        u16x8 v;
        if (r < NN) {
            const float* f1p = fc1_w + i * 3;
            const float* f2p = fc2_w + i * 3;
            const float* fgp = cls_w + i * 2;
            v[0] = f2bf(f1p[0]); v[1] = f2bf(f1p[1]); v[2] = f2bf(f1p[2]);
            v[3] = f2bf(f2p[0]); v[4] = f2bf(f2p[1]); v[5] = f2bf(f2p[2]);
            v[6] = f2bf(fgp[0]); v[7] = f2bf(fgp[1]);
        } else {
            #pragma unroll
            for (int j = 0; j < 8; ++j) v[j] = (unsigned short)0;
        }
        *(u16x8*)&s_fc[i * 8] = v;
    }
    if (t < 192) {
        int head = t >> 6, o = t & 63;
        const float* bp = (head == 0) ? gc1_b : (head == 1) ? gc2_b : gc_b;
        s_bias[head][o] = bp[o];
    }
    if (t < BPB * 2) ((unsigned*)s_mb)[t] = 0u;
    if (t < 8) s_xs[8 * 2 * 64 * XS_ST + t] = 0;
    __syncthreads();   // B1

    for (int i = t; i < BPB * NSEL; i += TPB) {
        int bt = i / NSEL, s = i - bt * NSEL;
        int idx = mask_idx[(b0 + bt) * NSEL + s];
        atomicOr(&s_mb[bt][idx >> 5], 1u << (idx & 31));
    }
    __syncthreads();   // B2

    // ---- dis1/dis2 via MFMA on staged bf16 adj ----
    if (w < 4) {
        unsigned mlo = s_mb[c][0], mhi = s_mb[c][1];
        bf16x8 M0, M1;
        #pragma unroll
        for (int e = 0; e < 8; ++e) {
            int l = g * 8 + e;
            M0[e] = __builtin_bit_cast(__bf16, (unsigned short)(((mlo >> l) & 1u) ? 0x3F80 : 0));
            M1[e] = __builtin_bit_cast(__bf16, (unsigned short)(((mhi >> l) & 1u) ? 0x3F80 : 0));
        }
        bf16x8 A0 = ldfrag(s_adjb, (w * 16 + c) * AD_BY + g * 16);
        bf16x8 A1 = ldfrag(s_adjb, (w * 16 + c) * AD_BY + 64 + g * 16);
        f32x4 Cd = {0.f, 0.f, 0.f, 0.f};
        Cd = MFMA(A0, M0, Cd);
        Cd = MFMA(A1, M1, Cd);
        #pragma unroll
        for (int i = 0; i < 4; ++i) {
            int j = w * 16 + g * 4 + i;
            unsigned bit = (j < 32) ? ((mlo >> j) & 1u) : ((mhi >> (j - 32)) & 1u);
            float s = bit ? Cd[i] : 0.0f;
            s_dis2[c][j] = (s > 0.0f) ? rsqrtf(s) : 0.0f;
        }
    } else if (w == 4) {
        bf16x8 ones;
        #pragma unroll
        for (int e = 0; e < 8; ++e)
            ones[e] = __builtin_bit_cast(__bf16, (unsigned short)0x3F80);
        #pragma unroll
        for (int mt = 0; mt < 4; ++mt) {
            bf16x8 A0 = ldfrag(s_adjb, (mt * 16 + c) * AD_BY + g * 16);
            bf16x8 A1 = ldfrag(s_adjb, (mt * 16 + c) * AD_BY + 64 + g * 16);
            f32x4 Cd = {0.f, 0.f, 0.f, 0.f};
            Cd = MFMA(A0, ones, Cd);
            Cd = MFMA(A1, ones, Cd);
            if (c == 0) {
                #pragma unroll
                for (int i = 0; i < 4; ++i) {
                    float d = Cd[i];
                    s_dis1[mt * 16 + g * 4 + i] = (d > 0.0f) ? rsqrtf(d) : 0.0f;
                }
            }
        }
    }
    __syncthreads();   // B3 -- last barrier; waves independent from here

    // ================= wave-private: 1 pair (2 batches) per wave =================
    unsigned short* xsW0 = &s_xs[(w * 2 + 0) * 64 * XS_ST];
    unsigned short* xsW1 = &s_xs[(w * 2 + 1) * 64 * XS_ST];
    unsigned short* utW  = &s_ut[w][0];
    {   // zero xs (both paths) + U buffer once
        unsigned* z = (unsigned*)xsW0;
        for (int i = lane; i < 64 * XS_ST; i += 64) z[i] = 0u;
        unsigned* zu = (unsigned*)utW;
        for (int i = lane; i < 16 * AD_ST / 2; i += 64) zu[i] = 0u;
    }

    bf16x8 adjA[4][2];
    #pragma unroll
    for (int mt = 0; mt < 4; ++mt)
        #pragma unroll
        for (int kf2 = 0; kf2 < 2; ++kf2)
            adjA[mt][kf2] = ldfrag(s_adjb, (mt * 16 + c) * AD_BY + kf2 * 64 + g * 16);

    const int f_c = (c < 5) ? c : (c < 10 ? c - 5 : 0);
    bf16x8 A1f[2][4], A2f[2][4];

    #pragma unroll
    for (int bi = 0; bi < 2; ++bi) {
        const int bb = w * 2 + bi;
        const int b  = b0 + bb;

        // ---- stage x0 (path1 = x, path2 = x*m) ----
        const float* xb = x + (size_t)b * NF;
        const unsigned mlo = s_mb[bb][0], mhi = s_mb[bb][1];
        for (int e = lane; e < NF; e += 64) {
            int n = e / 5, f = e - n * 5;
            float v = xb[e];
            unsigned bit = (n < 32) ? ((mlo >> n) & 1u) : ((mhi >> (n - 32)) & 1u);
            xsW0[n * XS_ST + f] = f2bf(v);
            xsW1[n * XS_ST + f] = f2bf(bit ? v : 0.0f);
        }

        // ---- per-lane dis selection ----
        float dsel[16];
        const float* dsp = (c < 5) ? s_dis1 : s_dis2[bb];
        #pragma unroll
        for (int mt = 0; mt < 4; ++mt)
            #pragma unroll
            for (int i = 0; i < 4; ++i)
                dsel[mt * 4 + i] = (c < 10) ? dsp[mt * 16 + g * 4 + i] : 0.0f;

        // ---- x0 fragments (C-layout: row = mt*16+g*4+i, col = c) ----
        const unsigned short* xsp = (c >= 5 && c < 10) ? xsW1 : xsW0;
        f32x4 xA[4];
        #pragma unroll
        for (int mt = 0; mt < 4; ++mt)
            #pragma unroll
            for (int i = 0; i < 4; ++i) {
                int r = mt * 16 + g * 4 + i;
                xA[mt][i] = (c < 10) ? bf2f(xsp[r * XS_ST + f_c]) : 0.0f;
            }

        // ---- U0 = dis .* x0 -> U^T[q=c][j], one b64 write per mt ----
        if (c < 10) {
            #pragma unroll
            for (int mt = 0; mt < 4; ++mt) {
                bf16x4 uv;
                uv[0] = (__bf16)(dsel[mt*4+0] * xA[mt][0]);
                uv[1] = (__bf16)(dsel[mt*4+1] * xA[mt][1]);
                uv[2] = (__bf16)(dsel[mt*4+2] * xA[mt][2]);
                uv[3] = (__bf16)(dsel[mt*4+3] * xA[mt][3]);
                *(bf16x4*)((char*)utW + c * U_BY + (mt * 16 + g * 4) * 2) = uv;
            }
        }

        // ---- Chebyshev k=1..3 (wave-private; independent MFMA pair) ----
        f32x4 x1f[4];
        #pragma unroll
        for (int k = 1; k <= 3; ++k) {
            const float cck = (k == 1) ? 1.0f : 2.0f;
            bf16x8 Uf0 = ldfrag(utW, c * U_BY + g * 16);
            bf16x8 Uf1 = ldfrag(utW, c * U_BY + 64 + g * 16);
            #pragma unroll
            for (int mt = 0; mt < 4; ++mt) {
                const f32x4 z = {0.f, 0.f, 0.f, 0.f};
                f32x4 Ca = MFMA(adjA[mt][0], Uf0, z);
                f32x4 Cb = MFMA(adjA[mt][1], Uf1, z);
                f32x4 Cv = Ca + Cb;
                f32x4 xn;
                #pragma unroll
                for (int i = 0; i < 4; ++i) {
                    float v = -cck * dsel[mt * 4 + i] * Cv[i];
                    if (k == 2) v -= xA[mt][i];
                    if (k == 3) v -= x1f[mt][i];
                    xn[i] = v;
                }
                if (c < 10) {
                    unsigned short* dst = (c < 5) ? xsW0 : xsW1;
                    #pragma unroll
                    for (int i = 0; i < 4; ++i)
                        dst[(mt * 16 + g * 4 + i) * XS_ST + k * 5 + f_c] = f2bf(xn[i]);
                    if (k < 3) {
                        bf16x4 uv;
                        uv[0] = (__bf16)(dsel[mt*4+0] * xn[0]);
                        uv[1] = (__bf16)(dsel[mt*4+1] * xn[1]);
                        uv[2] = (__bf16)(dsel[mt*4+2] * xn[2]);
                        uv[3] = (__bf16)(dsel[mt*4+3] * xn[3]);
                        *(bf16x4*)((char*)utW + c * U_BY + (mt * 16 + g * 4) * 2) = uv;
                    }
                }
                if (k == 1) x1f[mt] = xn;
            }
        }

        // ---- einsum A-frags for this batch ----
        #pragma unroll
        for (int mt = 0; mt < 4; ++mt) {
            A1f[bi][mt] = ldfrag(xsW0, (mt * 16 + c) * XS_BY + g * 16);
            A2f[bi][mt] = ldfrag(xsW1, (mt * 16 + c) * XS_BY + g * 16);
        }
    } // bi

    // ====== fused einsum + ReLU + FC: both batches per group, f32x2 tail ======
    f32x2 acc0[4], acc1[4];
    #pragma unroll
    for (int q = 0; q < 4; ++q) { acc0[q] = f32x2{0.f, 0.f}; acc1[q] = f32x2{0.f, 0.f}; }

    #pragma unroll
    for (int nt = 0; nt < 4; ++nt) {
        bf16x8 W1f = ldfrag(s_wt, (0 * 64 + nt * 16 + c) * WT_BY + g * 16);
        bf16x8 W2f = ldfrag(s_wt, (1 * 64 + nt * 16 + c) * WT_BY + g * 16);
        bf16x8 Wgf = ldfrag(s_wt, (2 * 64 + nt * 16 + c) * WT_BY + g * 16);
        const f32x2 bb12 = { s_bias[0][nt * 16 + c], s_bias[1][nt * 16 + c] };
        const float bbg = s_bias[2][nt * 16 + c];
        #pragma unroll
        for (int mt = 0; mt < 4; ++mt) {
            const f32x4 z = {0.f, 0.f, 0.f, 0.f};
            f32x4 C1a = MFMA(A1f[0][mt], W1f, z);
            f32x4 C1b = MFMA(A1f[1][mt], W1f, z);
            f32x4 C2a = MFMA(A2f[0][mt], W2f, z);
            f32x4 C2b = MFMA(A2f[1][mt], W2f, z);
            f32x4 Cga = MFMA(A1f[0][mt], Wgf, z);
            f32x4 Cgb = MFMA(A1f[1][mt], Wgf, z);
            #pragma unroll
            for (int i = 0; i < 4; ++i) {
                int r = mt * 16 + g * 4 + i;
                const u16x8 fcv = *(const u16x8*)((const char*)s_fc +
                                    ((r * CO + nt * 16 + c) << 4));
                f32x2 f01  = { bf2f(fcv[0]), bf2f(fcv[1]) };
                f32x2 f2f0 = { bf2f(fcv[2]), bf2f(fcv[3]) };
                f32x2 f12  = { bf2f(fcv[4]), bf2f(fcv[5]) };
                f32x2 fg   = { bf2f(fcv[6]), bf2f(fcv[7]) };
                f32x2 h12a = f32x2{C1a[i], C2a[i]} + bb12;
                h12a.x = fmaxf(h12a.x, 0.f); h12a.y = fmaxf(h12a.y, 0.f);
                f32x2 h12b = f32x2{C1b[i], C2b[i]} + bb12;
                h12b.x = fmaxf(h12b.x, 0.f); h12b.y = fmaxf(h12b.y, 0.f);
                float hga = fmaxf(Cga[i] + bbg, 0.f);
                float hgb = fmaxf(Cgb[i] + bbg, 0.f);
                acc0[0] += f32x2{h12a.x, h12a.x} * f01;
                acc0[1] += f32x2{h12a.x, h12a.y} * f2f0;
                acc0[2] += f32x2{h12a.y, h12a.y} * f12;
                acc0[3] += f32x2{hga,    hga   } * fg;
                acc1[0] += f32x2{h12b.x, h12b.x} * f01;
                acc1[1] += f32x2{h12b.x, h12b.y} * f2f0;
                acc1[2] += f32x2{h12b.y, h12b.y} * f12;
                acc1[3] += f32x2{hgb,    hgb   } * fg;
            }
        }
    }

    // ---- wave reduction + output ----
    float red[16] = {
        acc0[0].x, acc0[0].y, acc0[1].x, acc0[1].y,
        acc0[2].x, acc0[2].y, acc0[3].x, acc0[3].y,
        acc1[0].x, acc1[0].y, acc1[1].x, acc1[1].y,
        acc1[2].x, acc1[2].y, acc1[3].x, acc1[3].y
    };
    #pragma unroll
    for (int off = 32; off > 0; off >>= 1)
        #pragma unroll
        for (int q = 0; q < 16; ++q)
            red[q] += __shfl_down(red[q], off);

    if (lane == 0) {
        #pragma unroll
        for (int bi = 0; bi < 2; ++bi) {
            const int b = b0 + w * 2 + bi;
            float l0 = red[bi * 8 + 0] + fc1_b[0];
            float l1 = red[bi * 8 + 1] + fc1_b[1];
            float l2 = red[bi * 8 + 2] + fc1_b[2];
            float m0 = red[bi * 8 + 3] + fc2_b[0];
            float m1 = red[bi * 8 + 4] + fc2_b[1];
            float m2 = red[bi * 8 + 5] + fc2_b[2];
            float g0 = red[bi * 8 + 6] + cls_b[0];
            float g1 = red[bi * 8 + 7] + cls_b[1];
            float mx = fmaxf(g0, g1);
            float e0 = expf(g0 - mx), e1 = expf(g1 - mx);
            float inv = 1.0f / (e0 + e1);
            float p0 = e0 * inv, p1 = e1 * inv;
            out[b * 3 + 0] = l0 * p0 + m0 * p1;
            out[b * 3 + 1] = l1 * p0 + m1 * p1;
            out[b * 3 + 2] = l2 * p0 + m2 * p1;
        }
    }
}

extern "C" void kernel_launch(void* const* d_in, const int* in_sizes, int n_in,
                              void* d_out, int out_size, void* d_ws, size_t ws_size,
                              hipStream_t stream) {
    const float* x      = (const float*)d_in[0];
    const float* adj    = (const float*)d_in[1];
    const int*   midx   = (const int*)  d_in[2];
    const float* gc_w   = (const float*)d_in[3];
    const float* gc_b   = (const float*)d_in[4];
    const float* gc1_w  = (const float*)d_in[5];
    const float* gc1_b  = (const float*)d_in[6];
    const float* gc2_w  = (const float*)d_in[7];
    const float* gc2_b  = (const float*)d_in[8];
    const float* fc1_w  = (const float*)d_in[9];
    const float* fc1_b  = (const float*)d_in[10];
    const float* fc2_w  = (const float*)d_in[11];
    const float* fc2_b  = (const float*)d_in[12];
    const float* cls_w  = (const float*)d_in[13];
    const float* cls_b  = (const float*)d_in[14];
    float* o = (float*)d_out;
    hipLaunchKernelGGL(gnn_mfma, dim3(NBATCH / BPB), dim3(TPB), 0, stream,
        x, adj, midx, gc_w, gc_b, gc1_w, gc1_b, gc2_w, gc2_b,
        fc1_w, fc1_b, fc2_w, fc2_b, cls_w, cls_b, o);
}

// Round 16
// 29.112 us; speedup vs baseline: 6.4662x; 1.0655x over previous
//
#include <hip/hip_runtime.h>

#define NN 62
#define FF 5
#define KC 4
#define CO 64
#define NSEL 31
#define NF 310
#define NBATCH 4096
#define TPB 512        // 8 waves, 2/SIMD, one block/CU
#define BPB 16         // 8 waves x 2 batches
#define XS_ST 24       // xs row stride elems
#define XS_BY 48
#define AD_ST 72
#define AD_BY 144
#define WT_BY 80
#define U_BY  144

typedef __bf16 bf16x8 __attribute__((ext_vector_type(8)));
typedef __bf16 bf16x4 __attribute__((ext_vector_type(4)));
typedef float f32x4 __attribute__((ext_vector_type(4)));
typedef float f32x2 __attribute__((ext_vector_type(2)));
typedef unsigned short u16x8 __attribute__((ext_vector_type(8)));

#define MFMA(A, B, C) __builtin_amdgcn_mfma_f32_16x16x32_bf16((A), (B), (C), 0, 0, 0)

static __device__ __forceinline__ unsigned short f2bf(float f) {
    __bf16 b = (__bf16)f;
    return __builtin_bit_cast(unsigned short, b);
}
static __device__ __forceinline__ float bf2f(unsigned short s) {
    return __uint_as_float(((unsigned)s) << 16);
}
static __device__ __forceinline__ bf16x8 ldfrag(const unsigned short* p, int byte_off) {
    return *(const bf16x8*)((const char*)p + byte_off);
}

// R15 skeleton (sequential per-wave batches; 124 VGPR, no spill) plus:
//  - x prefetch for both batches before cheb(b0) (hides batch-1's global latency)
//  - division-free staging loops
//  - per-wave zeroing hoisted to kernel start (overlaps staging load latency)

__global__ __launch_bounds__(TPB) void gnn_mfma(
    const float* __restrict__ x, const float* __restrict__ adj,
    const int* __restrict__ mask_idx,
    const float* __restrict__ gc_w, const float* __restrict__ gc_b,
    const float* __restrict__ gc1_w, const float* __restrict__ gc1_b,
    const float* __restrict__ gc2_w, const float* __restrict__ gc2_b,
    const float* __restrict__ fc1_w, const float* __restrict__ fc1_b,
    const float* __restrict__ fc2_w, const float* __restrict__ fc2_b,
    const float* __restrict__ cls_w, const float* __restrict__ cls_b,
    float* __restrict__ out)
{
    __shared__ __align__(16) unsigned short s_adjb[64 * AD_ST];      // 9216 B
    __shared__ __align__(16) unsigned short s_wt[3 * 64 * 40];       // 15360 B
    __shared__ __align__(16) unsigned short s_fc[64 * CO * 8];       // 65536 B, rows 62/63 zero
    __shared__ float s_bias[3][64];                                  // 768 B
    __shared__ float s_dis1[64];                                     // 256 B
    __shared__ float s_dis2[BPB][64];                                // 4096 B
    __shared__ unsigned s_mb[BPB][2];                                // 128 B
    __shared__ __align__(16) unsigned short s_ut[8][16 * AD_ST];     // 18432 B per-wave U^T
    __shared__ __align__(16) unsigned short s_xs[8 * 2 * 64 * XS_ST + 8]; // 49168 B
    // total 162960 B <= 163840

    const int t = threadIdx.x;
    const int w = t >> 6, lane = t & 63;
    const int g = lane >> 4, c = lane & 15;
    const int b0 = blockIdx.x * BPB;

    unsigned short* xsW0 = &s_xs[(w * 2 + 0) * 64 * XS_ST];
    unsigned short* xsW1 = &s_xs[(w * 2 + 1) * 64 * XS_ST];
    unsigned short* utW  = &s_ut[w][0];

    // ---- per-wave zeroing FIRST (overlaps staging global-load latency) ----
    {
        unsigned* z = (unsigned*)xsW0;
        #pragma unroll
        for (int i = 0; i < (64 * XS_ST) / 64; ++i) z[lane + i * 64] = 0u;
        unsigned* zu = (unsigned*)utW;
        #pragma unroll
        for (int i = 0; i < (16 * AD_ST / 2) / 64; ++i) zu[lane + i * 64] = 0u;
    }
    if (t < 8) s_xs[8 * 2 * 64 * XS_ST + t] = 0;

    // ================= block-cooperative staging (division-free) =================
    for (int r = w; r < 64; r += 8) {                       // adj rows, lane = col
        float v = (r < NN && lane < NN) ? adj[r * NN + lane] : 0.0f;
        s_adjb[r * AD_ST + lane] = f2bf(v);
    }
    for (int i = t; i < 64 * 8; i += TPB) {                 // pad cols 64..71
        int r = i >> 3, cc = 64 + (i & 7);
        s_adjb[r * AD_ST + cc] = (unsigned short)0;
    }
    // wt: 192 (head,o) rows x 40 kf; thread handles 5 consecutive kf
    for (int row = w * 8 + (lane >> 3); row < 192; row += 64) {
        int head = row >> 6, o = row & 63;
        const float* wp = (head == 0) ? gc1_w : (head == 1) ? gc2_w : gc_w;
        int kf0 = (lane & 7) * 5;
        #pragma unroll
        for (int j = 0; j < 5; ++j) {
            int kf = kf0 + j;
            s_wt[row * 40 + kf] = f2bf((kf < KC * FF) ? wp[kf * CO + o] : 0.0f);
        }
    }
    for (int i = t; i < 64 * CO; i += TPB) {
        int r = i >> 6;
        u16x8 v;
        if (r < NN) {
            const float* f1p = fc1_w + i * 3;
            const float* f2p = fc2_w + i * 3;
            const float* fgp = cls_w + i * 2;
            v[0] = f2bf(f1p[0]); v[1] = f2bf(f1p[1]); v[2] = f2bf(f1p[2]);
            v[3] = f2bf(f2p[0]); v[4] = f2bf(f2p[1]); v[5] = f2bf(f2p[2]);
            v[6] = f2bf(fgp[0]); v[7] = f2bf(fgp[1]);
        } else {
            #pragma unroll
            for (int j = 0; j < 8; ++j) v[j] = (unsigned short)0;
        }
        *(u16x8*)&s_fc[i * 8] = v;
    }
    if (t < 192) {
        int head = t >> 6, o = t & 63;
        const float* bp = (head == 0) ? gc1_b : (head == 1) ? gc2_b : gc_b;
        s_bias[head][o] = bp[o];
    }
    if (t < BPB * 2) ((unsigned*)s_mb)[t] = 0u;
    __syncthreads();   // B1

    for (int i = t; i < BPB * NSEL; i += TPB) {
        int bt = i / NSEL, s = i - bt * NSEL;
        int idx = mask_idx[(b0 + bt) * NSEL + s];
        atomicOr(&s_mb[bt][idx >> 5], 1u << (idx & 31));
    }
    __syncthreads();   // B2

    // ---- dis1/dis2 via MFMA on staged bf16 adj ----
    if (w < 4) {
        unsigned mlo = s_mb[c][0], mhi = s_mb[c][1];
        bf16x8 M0, M1;
        #pragma unroll
        for (int e = 0; e < 8; ++e) {
            int l = g * 8 + e;
            M0[e] = __builtin_bit_cast(__bf16, (unsigned short)(((mlo >> l) & 1u) ? 0x3F80 : 0));
            M1[e] = __builtin_bit_cast(__bf16, (unsigned short)(((mhi >> l) & 1u) ? 0x3F80 : 0));
        }
        bf16x8 A0 = ldfrag(s_adjb, (w * 16 + c) * AD_BY + g * 16);
        bf16x8 A1 = ldfrag(s_adjb, (w * 16 + c) * AD_BY + 64 + g * 16);
        f32x4 Cd = {0.f, 0.f, 0.f, 0.f};
        Cd = MFMA(A0, M0, Cd);
        Cd = MFMA(A1, M1, Cd);
        #pragma unroll
        for (int i = 0; i < 4; ++i) {
            int j = w * 16 + g * 4 + i;
            unsigned bit = (j < 32) ? ((mlo >> j) & 1u) : ((mhi >> (j - 32)) & 1u);
            float s = bit ? Cd[i] : 0.0f;
            s_dis2[c][j] = (s > 0.0f) ? rsqrtf(s) : 0.0f;
        }
    } else if (w == 4) {
        bf16x8 ones;
        #pragma unroll
        for (int e = 0; e < 8; ++e)
            ones[e] = __builtin_bit_cast(__bf16, (unsigned short)0x3F80);
        #pragma unroll
        for (int mt = 0; mt < 4; ++mt) {
            bf16x8 A0 = ldfrag(s_adjb, (mt * 16 + c) * AD_BY + g * 16);
            bf16x8 A1 = ldfrag(s_adjb, (mt * 16 + c) * AD_BY + 64 + g * 16);
            f32x4 Cd = {0.f, 0.f, 0.f, 0.f};
            Cd = MFMA(A0, ones, Cd);
            Cd = MFMA(A1, ones, Cd);
            if (c == 0) {
                #pragma unroll
                for (int i = 0; i < 4; ++i) {
                    float d = Cd[i];
                    s_dis1[mt * 16 + g * 4 + i] = (d > 0.0f) ? rsqrtf(d) : 0.0f;
                }
            }
        }
    }
    __syncthreads();   // B3 -- last barrier; waves independent from here

    bf16x8 adjA[4][2];
    #pragma unroll
    for (int mt = 0; mt < 4; ++mt)
        #pragma unroll
        for (int kf2 = 0; kf2 < 2; ++kf2)
            adjA[mt][kf2] = ldfrag(s_adjb, (mt * 16 + c) * AD_BY + kf2 * 64 + g * 16);

    const int f_c = (c < 5) ? c : (c < 10 ? c - 5 : 0);
    const int bbp0 = w * 2, bbp1 = w * 2 + 1;

    // ---- prefetch BOTH batches' x rows up front (named regs, rule-#20 safe) ----
    float xpre0[5], xpre1[5];
    {
        const float* xb0 = x + (size_t)(b0 + bbp0) * NF;
        const float* xb1 = x + (size_t)(b0 + bbp1) * NF;
        #pragma unroll
        for (int it = 0; it < 5; ++it) {
            int e = lane + it * 64;
            xpre0[it] = (e < NF) ? xb0[e] : 0.0f;
            xpre1[it] = (e < NF) ? xb1[e] : 0.0f;
        }
    }

    bf16x8 A1f[2][4], A2f[2][4];

    #pragma unroll
    for (int bi = 0; bi < 2; ++bi) {
        const int bb = w * 2 + bi;

        // ---- stage x0 from prefetched regs (path1 = x, path2 = x*m) ----
        const unsigned mlo = s_mb[bb][0], mhi = s_mb[bb][1];
        #pragma unroll
        for (int it = 0; it < 5; ++it) {
            int e = lane + it * 64;
            if (e < NF) {
                int n = e / 5, f = e - n * 5;
                float v = (bi == 0) ? xpre0[it] : xpre1[it];
                unsigned bit = (n < 32) ? ((mlo >> n) & 1u) : ((mhi >> (n - 32)) & 1u);
                xsW0[n * XS_ST + f] = f2bf(v);
                xsW1[n * XS_ST + f] = f2bf(bit ? v : 0.0f);
            }
        }

        // ---- per-lane dis selection ----
        float dsel[16];
        const float* dsp = (c < 5) ? s_dis1 : s_dis2[bb];
        #pragma unroll
        for (int mt = 0; mt < 4; ++mt)
            #pragma unroll
            for (int i = 0; i < 4; ++i)
                dsel[mt * 4 + i] = (c < 10) ? dsp[mt * 16 + g * 4 + i] : 0.0f;

        // ---- x0 fragments (C-layout: row = mt*16+g*4+i, col = c) ----
        const unsigned short* xsp = (c >= 5 && c < 10) ? xsW1 : xsW0;
        f32x4 xA[4];
        #pragma unroll
        for (int mt = 0; mt < 4; ++mt)
            #pragma unroll
            for (int i = 0; i < 4; ++i) {
                int r = mt * 16 + g * 4 + i;
                xA[mt][i] = (c < 10) ? bf2f(xsp[r * XS_ST + f_c]) : 0.0f;
            }

        // ---- U0 = dis .* x0 -> U^T[q=c][j], one b64 write per mt ----
        if (c < 10) {
            #pragma unroll
            for (int mt = 0; mt < 4; ++mt) {
                bf16x4 uv;
                uv[0] = (__bf16)(dsel[mt*4+0] * xA[mt][0]);
                uv[1] = (__bf16)(dsel[mt*4+1] * xA[mt][1]);
                uv[2] = (__bf16)(dsel[mt*4+2] * xA[mt][2]);
                uv[3] = (__bf16)(dsel[mt*4+3] * xA[mt][3]);
                *(bf16x4*)((char*)utW + c * U_BY + (mt * 16 + g * 4) * 2) = uv;
            }
        }

        // ---- Chebyshev k=1..3 (wave-private; independent MFMA pair) ----
        f32x4 x1f[4];
        #pragma unroll
        for (int k = 1; k <= 3; ++k) {
            const float cck = (k == 1) ? 1.0f : 2.0f;
            bf16x8 Uf0 = ldfrag(utW, c * U_BY + g * 16);
            bf16x8 Uf1 = ldfrag(utW, c * U_BY + 64 + g * 16);
            #pragma unroll
            for (int mt = 0; mt < 4; ++mt) {
                const f32x4 z = {0.f, 0.f, 0.f, 0.f};
                f32x4 Ca = MFMA(adjA[mt][0], Uf0, z);
                f32x4 Cb = MFMA(adjA[mt][1], Uf1, z);
                f32x4 Cv = Ca + Cb;
                f32x4 xn;
                #pragma unroll
                for (int i = 0; i < 4; ++i) {
                    float v = -cck * dsel[mt * 4 + i] * Cv[i];
                    if (k == 2) v -= xA[mt][i];
                    if (k == 3) v -= x1f[mt][i];
                    xn[i] = v;
                }
                if (c < 10) {
                    unsigned short* dst = (c < 5) ? xsW0 : xsW1;
                    #pragma unroll
                    for (int i = 0; i < 4; ++i)
                        dst[(mt * 16 + g * 4 + i) * XS_ST + k * 5 + f_c] = f2bf(xn[i]);
                    if (k < 3) {
                        bf16x4 uv;
                        uv[0] = (__bf16)(dsel[mt*4+0] * xn[0]);
                        uv[1] = (__bf16)(dsel[mt*4+1] * xn[1]);
                        uv[2] = (__bf16)(dsel[mt*4+2] * xn[2]);
                        uv[3] = (__bf16)(dsel[mt*4+3] * xn[3]);
                        *(bf16x4*)((char*)utW + c * U_BY + (mt * 16 + g * 4) * 2) = uv;
                    }
                }
                if (k == 1) x1f[mt] = xn;
            }
        }

        // ---- einsum A-frags for this batch ----
        #pragma unroll
        for (int mt = 0; mt < 4; ++mt) {
            A1f[bi][mt] = ldfrag(xsW0, (mt * 16 + c) * XS_BY + g * 16);
            A2f[bi][mt] = ldfrag(xsW1, (mt * 16 + c) * XS_BY + g * 16);
        }
    } // bi

    // ====== fused einsum + ReLU + FC: both batches per group, f32x2 tail ======
    f32x2 acc0[4], acc1[4];
    #pragma unroll
    for (int q = 0; q < 4; ++q) { acc0[q] = f32x2{0.f, 0.f}; acc1[q] = f32x2{0.f, 0.f}; }

    #pragma unroll
    for (int nt = 0; nt < 4; ++nt) {
        bf16x8 W1f = ldfrag(s_wt, (0 * 64 + nt * 16 + c) * WT_BY + g * 16);
        bf16x8 W2f = ldfrag(s_wt, (1 * 64 + nt * 16 + c) * WT_BY + g * 16);
        bf16x8 Wgf = ldfrag(s_wt, (2 * 64 + nt * 16 + c) * WT_BY + g * 16);
        const f32x2 bb12 = { s_bias[0][nt * 16 + c], s_bias[1][nt * 16 + c] };
        const float bbg = s_bias[2][nt * 16 + c];
        #pragma unroll
        for (int mt = 0; mt < 4; ++mt) {
            const f32x4 z = {0.f, 0.f, 0.f, 0.f};
            f32x4 C1a = MFMA(A1f[0][mt], W1f, z);
            f32x4 C1b = MFMA(A1f[1][mt], W1f, z);
            f32x4 C2a = MFMA(A2f[0][mt], W2f, z);
            f32x4 C2b = MFMA(A2f[1][mt], W2f, z);
            f32x4 Cga = MFMA(A1f[0][mt], Wgf, z);
            f32x4 Cgb = MFMA(A1f[1][mt], Wgf, z);
            #pragma unroll
            for (int i = 0; i < 4; ++i) {
                int r = mt * 16 + g * 4 + i;
                const u16x8 fcv = *(const u16x8*)((const char*)s_fc +
                                    ((r * CO + nt * 16 + c) << 4));
                f32x2 f01  = { bf2f(fcv[0]), bf2f(fcv[1]) };
                f32x2 f2f0 = { bf2f(fcv[2]), bf2f(fcv[3]) };
                f32x2 f12  = { bf2f(fcv[4]), bf2f(fcv[5]) };
                f32x2 fg   = { bf2f(fcv[6]), bf2f(fcv[7]) };
                f32x2 h12a = f32x2{C1a[i], C2a[i]} + bb12;
                h12a.x = fmaxf(h12a.x, 0.f); h12a.y = fmaxf(h12a.y, 0.f);
                f32x2 h12b = f32x2{C1b[i], C2b[i]} + bb12;
                h12b.x = fmaxf(h12b.x, 0.f); h12b.y = fmaxf(h12b.y, 0.f);
                float hga = fmaxf(Cga[i] + bbg, 0.f);
                float hgb = fmaxf(Cgb[i] + bbg, 0.f);
                acc0[0] += f32x2{h12a.x, h12a.x} * f01;
                acc0[1] += f32x2{h12a.x, h12a.y} * f2f0;
                acc0[2] += f32x2{h12a.y, h12a.y} * f12;
                acc0[3] += f32x2{hga,    hga   } * fg;
                acc1[0] += f32x2{h12b.x, h12b.x} * f01;
                acc1[1] += f32x2{h12b.x, h12b.y} * f2f0;
                acc1[2] += f32x2{h12b.y, h12b.y} * f12;
                acc1[3] += f32x2{hgb,    hgb   } * fg;
            }
        }
    }

    // ---- wave reduction + output ----
    float red[16] = {
        acc0[0].x, acc0[0].y, acc0[1].x, acc0[1].y,
        acc0[2].x, acc0[2].y, acc0[3].x, acc0[3].y,
        acc1[0].x, acc1[0].y, acc1[1].x, acc1[1].y,
        acc1[2].x, acc1[2].y, acc1[3].x, acc1[3].y
    };
    #pragma unroll
    for (int off = 32; off > 0; off >>= 1)
        #pragma unroll
        for (int q = 0; q < 16; ++q)
            red[q] += __shfl_down(red[q], off);

    if (lane == 0) {
        #pragma unroll
        for (int bi = 0; bi < 2; ++bi) {
            const int b = b0 + w * 2 + bi;
            float l0 = red[bi * 8 + 0] + fc1_b[0];
            float l1 = red[bi * 8 + 1] + fc1_b[1];
            float l2 = red[bi * 8 + 2] + fc1_b[2];
            float m0 = red[bi * 8 + 3] + fc2_b[0];
            float m1 = red[bi * 8 + 4] + fc2_b[1];
            float m2 = red[bi * 8 + 5] + fc2_b[2];
            float g0 = red[bi * 8 + 6] + cls_b[0];
            float g1 = red[bi * 8 + 7] + cls_b[1];
            float mx = fmaxf(g0, g1);
            float e0 = expf(g0 - mx), e1 = expf(g1 - mx);
            float inv = 1.0f / (e0 + e1);
            float p0 = e0 * inv, p1 = e1 * inv;
            out[b * 3 + 0] = l0 * p0 + m0 * p1;
            out[b * 3 + 1] = l1 * p0 + m1 * p1;
            out[b * 3 + 2] = l2 * p0 + m2 * p1;
        }
    }
}

extern "C" void kernel_launch(void* const* d_in, const int* in_sizes, int n_in,
                              void* d_out, int out_size, void* d_ws, size_t ws_size,
                              hipStream_t stream) {
    const float* x      = (const float*)d_in[0];
    const float* adj    = (const float*)d_in[1];
    const int*   midx   = (const int*)  d_in[2];
    const float* gc_w   = (const float*)d_in[3];
    const float* gc_b   = (const float*)d_in[4];
    const float* gc1_w  = (const float*)d_in[5];
    const float* gc1_b  = (const float*)d_in[6];
    const float* gc2_w  = (const float*)d_in[7];
    const float* gc2_b  = (const float*)d_in[8];
    const float* fc1_w  = (const float*)d_in[9];
    const float* fc1_b  = (const float*)d_in[10];
    const float* fc2_w  = (const float*)d_in[11];
    const float* fc2_b  = (const float*)d_in[12];
    const float* cls_w  = (const float*)d_in[13];
    const float* cls_b  = (const float*)d_in[14];
    float* o = (float*)d_out;
    hipLaunchKernelGGL(gnn_mfma, dim3(NBATCH / BPB), dim3(TPB), 0, stream,
        x, adj, midx, gc_w, gc_b, gc1_w, gc1_b, gc2_w, gc2_b,
        fc1_w, fc1_b, fc2_w, fc2_b, cls_w, cls_b, o);
}

// Round 17
// 28.951 us; speedup vs baseline: 6.5021x; 1.0056x over previous
//
#include <hip/hip_runtime.h>

#define NN 62
#define FF 5
#define KC 4
#define CO 64
#define NSEL 31
#define NF 310
#define NBATCH 4096
#define TPB 512        // 8 waves, 2/SIMD, one block/CU
#define BPB 16         // 8 waves x 2 batches
#define XS_ST 24       // xs row stride elems (16B-aligned rows for b128 A-frag reads)
#define XS_BY 48
#define AD_ST 72
#define AD_BY 144
#define WT_BY 80
#define U_BY  144

typedef __bf16 bf16x8 __attribute__((ext_vector_type(8)));
typedef __bf16 bf16x4 __attribute__((ext_vector_type(4)));
typedef float f32x4 __attribute__((ext_vector_type(4)));
typedef float f32x2 __attribute__((ext_vector_type(2)));
typedef unsigned short u16x8 __attribute__((ext_vector_type(8)));

#define MFMA(A, B, C) __builtin_amdgcn_mfma_f32_16x16x32_bf16((A), (B), (C), 0, 0, 0)

static __device__ __forceinline__ unsigned short f2bf(float f) {
    __bf16 b = (__bf16)f;
    return __builtin_bit_cast(unsigned short, b);
}
static __device__ __forceinline__ float bf2f(unsigned short s) {
    return __uint_as_float(((unsigned)s) << 16);
}
static __device__ __forceinline__ bf16x8 ldfrag(const unsigned short* p, int byte_off) {
    return *(const bf16x8*)((const char*)p + byte_off);
}

// R16 skeleton (sequential per-wave batches; no spill) + T5 s_setprio around
// MFMA clusters (waves are phase-independent post-B3 -> scheduler can favor
// MFMA-ready waves; catalog: +4-7% in analogous independent-wave structure)
// + fcv reads hoisted per (nt,mt) group (batch the 4 b128 issues).

__global__ __launch_bounds__(TPB) void gnn_mfma(
    const float* __restrict__ x, const float* __restrict__ adj,
    const int* __restrict__ mask_idx,
    const float* __restrict__ gc_w, const float* __restrict__ gc_b,
    const float* __restrict__ gc1_w, const float* __restrict__ gc1_b,
    const float* __restrict__ gc2_w, const float* __restrict__ gc2_b,
    const float* __restrict__ fc1_w, const float* __restrict__ fc1_b,
    const float* __restrict__ fc2_w, const float* __restrict__ fc2_b,
    const float* __restrict__ cls_w, const float* __restrict__ cls_b,
    float* __restrict__ out)
{
    __shared__ __align__(16) unsigned short s_adjb[64 * AD_ST];      // 9216 B
    __shared__ __align__(16) unsigned short s_wt[3 * 64 * 40];       // 15360 B
    __shared__ __align__(16) unsigned short s_fc[64 * CO * 8];       // 65536 B, rows 62/63 zero
    __shared__ float s_bias[3][64];                                  // 768 B
    __shared__ float s_dis1[64];                                     // 256 B
    __shared__ float s_dis2[BPB][64];                                // 4096 B
    __shared__ unsigned s_mb[BPB][2];                                // 128 B
    __shared__ __align__(16) unsigned short s_ut[8][16 * AD_ST];     // 18432 B per-wave U^T
    __shared__ __align__(16) unsigned short s_xs[8 * 2 * 64 * XS_ST + 8]; // 49168 B
    // total 162960 B <= 163840

    const int t = threadIdx.x;
    const int w = t >> 6, lane = t & 63;
    const int g = lane >> 4, c = lane & 15;
    const int b0 = blockIdx.x * BPB;

    unsigned short* xsW0 = &s_xs[(w * 2 + 0) * 64 * XS_ST];
    unsigned short* xsW1 = &s_xs[(w * 2 + 1) * 64 * XS_ST];
    unsigned short* utW  = &s_ut[w][0];

    // ---- per-wave zeroing FIRST (overlaps staging global-load latency) ----
    {
        unsigned* z = (unsigned*)xsW0;
        #pragma unroll
        for (int i = 0; i < (64 * XS_ST) / 64; ++i) z[lane + i * 64] = 0u;
        unsigned* zu = (unsigned*)utW;
        #pragma unroll
        for (int i = 0; i < (16 * AD_ST / 2) / 64; ++i) zu[lane + i * 64] = 0u;
    }
    if (t < 8) s_xs[8 * 2 * 64 * XS_ST + t] = 0;

    // ================= block-cooperative staging (division-free) =================
    for (int r = w; r < 64; r += 8) {                       // adj rows, lane = col
        float v = (r < NN && lane < NN) ? adj[r * NN + lane] : 0.0f;
        s_adjb[r * AD_ST + lane] = f2bf(v);
    }
    for (int i = t; i < 64 * 8; i += TPB) {                 // pad cols 64..71
        int r = i >> 3, cc = 64 + (i & 7);
        s_adjb[r * AD_ST + cc] = (unsigned short)0;
    }
    // wt: 192 (head,o) rows x 40 kf; thread handles 5 consecutive kf
    for (int row = w * 8 + (lane >> 3); row < 192; row += 64) {
        int head = row >> 6, o = row & 63;
        const float* wp = (head == 0) ? gc1_w : (head == 1) ? gc2_w : gc_w;
        int kf0 = (lane & 7) * 5;
        #pragma unroll
        for (int j = 0; j < 5; ++j) {
            int kf = kf0 + j;
            s_wt[row * 40 + kf] = f2bf((kf < KC * FF) ? wp[kf * CO + o] : 0.0f);
        }
    }
    for (int i = t; i < 64 * CO; i += TPB) {
        int r = i >> 6;
        u16x8 v;
        if (r < NN) {
            const float* f1p = fc1_w + i * 3;
            const float* f2p = fc2_w + i * 3;
            const float* fgp = cls_w + i * 2;
            v[0] = f2bf(f1p[0]); v[1] = f2bf(f1p[1]); v[2] = f2bf(f1p[2]);
            v[3] = f2bf(f2p[0]); v[4] = f2bf(f2p[1]); v[5] = f2bf(f2p[2]);
            v[6] = f2bf(fgp[0]); v[7] = f2bf(fgp[1]);
        } else {
            #pragma unroll
            for (int j = 0; j < 8; ++j) v[j] = (unsigned short)0;
        }
        *(u16x8*)&s_fc[i * 8] = v;
    }
    if (t < 192) {
        int head = t >> 6, o = t & 63;
        const float* bp = (head == 0) ? gc1_b : (head == 1) ? gc2_b : gc_b;
        s_bias[head][o] = bp[o];
    }
    if (t < BPB * 2) ((unsigned*)s_mb)[t] = 0u;
    __syncthreads();   // B1

    for (int i = t; i < BPB * NSEL; i += TPB) {
        int bt = i / NSEL, s = i - bt * NSEL;
        int idx = mask_idx[(b0 + bt) * NSEL + s];
        atomicOr(&s_mb[bt][idx >> 5], 1u << (idx & 31));
    }
    __syncthreads();   // B2

    // ---- dis1/dis2 via MFMA on staged bf16 adj ----
    if (w < 4) {
        unsigned mlo = s_mb[c][0], mhi = s_mb[c][1];
        bf16x8 M0, M1;
        #pragma unroll
        for (int e = 0; e < 8; ++e) {
            int l = g * 8 + e;
            M0[e] = __builtin_bit_cast(__bf16, (unsigned short)(((mlo >> l) & 1u) ? 0x3F80 : 0));
            M1[e] = __builtin_bit_cast(__bf16, (unsigned short)(((mhi >> l) & 1u) ? 0x3F80 : 0));
        }
        bf16x8 A0 = ldfrag(s_adjb, (w * 16 + c) * AD_BY + g * 16);
        bf16x8 A1 = ldfrag(s_adjb, (w * 16 + c) * AD_BY + 64 + g * 16);
        f32x4 Cd = {0.f, 0.f, 0.f, 0.f};
        Cd = MFMA(A0, M0, Cd);
        Cd = MFMA(A1, M1, Cd);
        #pragma unroll
        for (int i = 0; i < 4; ++i) {
            int j = w * 16 + g * 4 + i;
            unsigned bit = (j < 32) ? ((mlo >> j) & 1u) : ((mhi >> (j - 32)) & 1u);
            float s = bit ? Cd[i] : 0.0f;
            s_dis2[c][j] = (s > 0.0f) ? rsqrtf(s) : 0.0f;
        }
    } else if (w == 4) {
        bf16x8 ones;
        #pragma unroll
        for (int e = 0; e < 8; ++e)
            ones[e] = __builtin_bit_cast(__bf16, (unsigned short)0x3F80);
        #pragma unroll
        for (int mt = 0; mt < 4; ++mt) {
            bf16x8 A0 = ldfrag(s_adjb, (mt * 16 + c) * AD_BY + g * 16);
            bf16x8 A1 = ldfrag(s_adjb, (mt * 16 + c) * AD_BY + 64 + g * 16);
            f32x4 Cd = {0.f, 0.f, 0.f, 0.f};
            Cd = MFMA(A0, ones, Cd);
            Cd = MFMA(A1, ones, Cd);
            if (c == 0) {
                #pragma unroll
                for (int i = 0; i < 4; ++i) {
                    float d = Cd[i];
                    s_dis1[mt * 16 + g * 4 + i] = (d > 0.0f) ? rsqrtf(d) : 0.0f;
                }
            }
        }
    }
    __syncthreads();   // B3 -- last barrier; waves independent from here

    bf16x8 adjA[4][2];
    #pragma unroll
    for (int mt = 0; mt < 4; ++mt)
        #pragma unroll
        for (int kf2 = 0; kf2 < 2; ++kf2)
            adjA[mt][kf2] = ldfrag(s_adjb, (mt * 16 + c) * AD_BY + kf2 * 64 + g * 16);

    const int f_c = (c < 5) ? c : (c < 10 ? c - 5 : 0);
    const int bbp0 = w * 2, bbp1 = w * 2 + 1;

    // ---- prefetch BOTH batches' x rows up front (named regs, rule-#20 safe) ----
    float xpre0[5], xpre1[5];
    {
        const float* xb0 = x + (size_t)(b0 + bbp0) * NF;
        const float* xb1 = x + (size_t)(b0 + bbp1) * NF;
        #pragma unroll
        for (int it = 0; it < 5; ++it) {
            int e = lane + it * 64;
            xpre0[it] = (e < NF) ? xb0[e] : 0.0f;
            xpre1[it] = (e < NF) ? xb1[e] : 0.0f;
        }
    }

    bf16x8 A1f[2][4], A2f[2][4];

    #pragma unroll
    for (int bi = 0; bi < 2; ++bi) {
        const int bb = w * 2 + bi;

        // ---- stage x0 from prefetched regs (path1 = x, path2 = x*m) ----
        const unsigned mlo = s_mb[bb][0], mhi = s_mb[bb][1];
        #pragma unroll
        for (int it = 0; it < 5; ++it) {
            int e = lane + it * 64;
            if (e < NF) {
                int n = e / 5, f = e - n * 5;
                float v = (bi == 0) ? xpre0[it] : xpre1[it];
                unsigned bit = (n < 32) ? ((mlo >> n) & 1u) : ((mhi >> (n - 32)) & 1u);
                xsW0[n * XS_ST + f] = f2bf(v);
                xsW1[n * XS_ST + f] = f2bf(bit ? v : 0.0f);
            }
        }

        // ---- per-lane dis selection ----
        float dsel[16];
        const float* dsp = (c < 5) ? s_dis1 : s_dis2[bb];
        #pragma unroll
        for (int mt = 0; mt < 4; ++mt)
            #pragma unroll
            for (int i = 0; i < 4; ++i)
                dsel[mt * 4 + i] = (c < 10) ? dsp[mt * 16 + g * 4 + i] : 0.0f;

        // ---- x0 fragments (C-layout: row = mt*16+g*4+i, col = c) ----
        const unsigned short* xsp = (c >= 5 && c < 10) ? xsW1 : xsW0;
        f32x4 xA[4];
        #pragma unroll
        for (int mt = 0; mt < 4; ++mt)
            #pragma unroll
            for (int i = 0; i < 4; ++i) {
                int r = mt * 16 + g * 4 + i;
                xA[mt][i] = (c < 10) ? bf2f(xsp[r * XS_ST + f_c]) : 0.0f;
            }

        // ---- U0 = dis .* x0 -> U^T[q=c][j], one b64 write per mt ----
        if (c < 10) {
            #pragma unroll
            for (int mt = 0; mt < 4; ++mt) {
                bf16x4 uv;
                uv[0] = (__bf16)(dsel[mt*4+0] * xA[mt][0]);
                uv[1] = (__bf16)(dsel[mt*4+1] * xA[mt][1]);
                uv[2] = (__bf16)(dsel[mt*4+2] * xA[mt][2]);
                uv[3] = (__bf16)(dsel[mt*4+3] * xA[mt][3]);
                *(bf16x4*)((char*)utW + c * U_BY + (mt * 16 + g * 4) * 2) = uv;
            }
        }

        // ---- Chebyshev k=1..3 (wave-private; setprio around MFMA pair) ----
        f32x4 x1f[4];
        #pragma unroll
        for (int k = 1; k <= 3; ++k) {
            const float cck = (k == 1) ? 1.0f : 2.0f;
            bf16x8 Uf0 = ldfrag(utW, c * U_BY + g * 16);
            bf16x8 Uf1 = ldfrag(utW, c * U_BY + 64 + g * 16);
            #pragma unroll
            for (int mt = 0; mt < 4; ++mt) {
                const f32x4 z = {0.f, 0.f, 0.f, 0.f};
                __builtin_amdgcn_s_setprio(1);
                f32x4 Ca = MFMA(adjA[mt][0], Uf0, z);
                f32x4 Cb = MFMA(adjA[mt][1], Uf1, z);
                __builtin_amdgcn_s_setprio(0);
                f32x4 Cv = Ca + Cb;
                f32x4 xn;
                #pragma unroll
                for (int i = 0; i < 4; ++i) {
                    float v = -cck * dsel[mt * 4 + i] * Cv[i];
                    if (k == 2) v -= xA[mt][i];
                    if (k == 3) v -= x1f[mt][i];
                    xn[i] = v;
                }
                if (c < 10) {
                    unsigned short* dst = (c < 5) ? xsW0 : xsW1;
                    #pragma unroll
                    for (int i = 0; i < 4; ++i)
                        dst[(mt * 16 + g * 4 + i) * XS_ST + k * 5 + f_c] = f2bf(xn[i]);
                    if (k < 3) {
                        bf16x4 uv;
                        uv[0] = (__bf16)(dsel[mt*4+0] * xn[0]);
                        uv[1] = (__bf16)(dsel[mt*4+1] * xn[1]);
                        uv[2] = (__bf16)(dsel[mt*4+2] * xn[2]);
                        uv[3] = (__bf16)(dsel[mt*4+3] * xn[3]);
                        *(bf16x4*)((char*)utW + c * U_BY + (mt * 16 + g * 4) * 2) = uv;
                    }
                }
                if (k == 1) x1f[mt] = xn;
            }
        }

        // ---- einsum A-frags for this batch ----
        #pragma unroll
        for (int mt = 0; mt < 4; ++mt) {
            A1f[bi][mt] = ldfrag(xsW0, (mt * 16 + c) * XS_BY + g * 16);
            A2f[bi][mt] = ldfrag(xsW1, (mt * 16 + c) * XS_BY + g * 16);
        }
    } // bi

    // ====== fused einsum + ReLU + FC: both batches per group, f32x2 tail ======
    f32x2 acc0[4], acc1[4];
    #pragma unroll
    for (int q = 0; q < 4; ++q) { acc0[q] = f32x2{0.f, 0.f}; acc1[q] = f32x2{0.f, 0.f}; }

    #pragma unroll
    for (int nt = 0; nt < 4; ++nt) {
        bf16x8 W1f = ldfrag(s_wt, (0 * 64 + nt * 16 + c) * WT_BY + g * 16);
        bf16x8 W2f = ldfrag(s_wt, (1 * 64 + nt * 16 + c) * WT_BY + g * 16);
        bf16x8 Wgf = ldfrag(s_wt, (2 * 64 + nt * 16 + c) * WT_BY + g * 16);
        const f32x2 bb12 = { s_bias[0][nt * 16 + c], s_bias[1][nt * 16 + c] };
        const float bbg = s_bias[2][nt * 16 + c];
        #pragma unroll
        for (int mt = 0; mt < 4; ++mt) {
            const f32x4 z = {0.f, 0.f, 0.f, 0.f};
            __builtin_amdgcn_s_setprio(1);
            f32x4 C1a = MFMA(A1f[0][mt], W1f, z);
            f32x4 C1b = MFMA(A1f[1][mt], W1f, z);
            f32x4 C2a = MFMA(A2f[0][mt], W2f, z);
            f32x4 C2b = MFMA(A2f[1][mt], W2f, z);
            f32x4 Cga = MFMA(A1f[0][mt], Wgf, z);
            f32x4 Cgb = MFMA(A1f[1][mt], Wgf, z);
            __builtin_amdgcn_s_setprio(0);
            // hoisted fcv reads: 4 independent b128 issues, one latency exposure
            const int rb = (mt * 16 + g * 4) * CO + nt * 16 + c;
            const u16x8 fcv0 = *(const u16x8*)((const char*)s_fc + ((rb + 0 * CO) << 4));
            const u16x8 fcv1 = *(const u16x8*)((const char*)s_fc + ((rb + 1 * CO) << 4));
            const u16x8 fcv2 = *(const u16x8*)((const char*)s_fc + ((rb + 2 * CO) << 4));
            const u16x8 fcv3 = *(const u16x8*)((const char*)s_fc + ((rb + 3 * CO) << 4));
            #pragma unroll
            for (int i = 0; i < 4; ++i) {
                const u16x8 fcv = (i == 0) ? fcv0 : (i == 1) ? fcv1 : (i == 2) ? fcv2 : fcv3;
                f32x2 f01  = { bf2f(fcv[0]), bf2f(fcv[1]) };
                f32x2 f2f0 = { bf2f(fcv[2]), bf2f(fcv[3]) };
                f32x2 f12  = { bf2f(fcv[4]), bf2f(fcv[5]) };
                f32x2 fg   = { bf2f(fcv[6]), bf2f(fcv[7]) };
                f32x2 h12a = f32x2{C1a[i], C2a[i]} + bb12;
                h12a.x = fmaxf(h12a.x, 0.f); h12a.y = fmaxf(h12a.y, 0.f);
                f32x2 h12b = f32x2{C1b[i], C2b[i]} + bb12;
                h12b.x = fmaxf(h12b.x, 0.f); h12b.y = fmaxf(h12b.y, 0.f);
                float hga = fmaxf(Cga[i] + bbg, 0.f);
                float hgb = fmaxf(Cgb[i] + bbg, 0.f);
                acc0[0] += f32x2{h12a.x, h12a.x} * f01;
                acc0[1] += f32x2{h12a.x, h12a.y} * f2f0;
                acc0[2] += f32x2{h12a.y, h12a.y} * f12;
                acc0[3] += f32x2{hga,    hga   } * fg;
                acc1[0] += f32x2{h12b.x, h12b.x} * f01;
                acc1[1] += f32x2{h12b.x, h12b.y} * f2f0;
                acc1[2] += f32x2{h12b.y, h12b.y} * f12;
                acc1[3] += f32x2{hgb,    hgb   } * fg;
            }
        }
    }

    // ---- wave reduction + output ----
    float red[16] = {
        acc0[0].x, acc0[0].y, acc0[1].x, acc0[1].y,
        acc0[2].x, acc0[2].y, acc0[3].x, acc0[3].y,
        acc1[0].x, acc1[0].y, acc1[1].x, acc1[1].y,
        acc1[2].x, acc1[2].y, acc1[3].x, acc1[3].y
    };
    #pragma unroll
    for (int off = 32; off > 0; off >>= 1)
        #pragma unroll
        for (int q = 0; q < 16; ++q)
            red[q] += __shfl_down(red[q], off);

    if (lane == 0) {
        #pragma unroll
        for (int bi = 0; bi < 2; ++bi) {
            const int b = b0 + w * 2 + bi;
            float l0 = red[bi * 8 + 0] + fc1_b[0];
            float l1 = red[bi * 8 + 1] + fc1_b[1];
            float l2 = red[bi * 8 + 2] + fc1_b[2];
            float m0 = red[bi * 8 + 3] + fc2_b[0];
            float m1 = red[bi * 8 + 4] + fc2_b[1];
            float m2 = red[bi * 8 + 5] + fc2_b[2];
            float g0 = red[bi * 8 + 6] + cls_b[0];
            float g1 = red[bi * 8 + 7] + cls_b[1];
            float mx = fmaxf(g0, g1);
            float e0 = expf(g0 - mx), e1 = expf(g1 - mx);
            float inv = 1.0f / (e0 + e1);
            float p0 = e0 * inv, p1 = e1 * inv;
            out[b * 3 + 0] = l0 * p0 + m0 * p1;
            out[b * 3 + 1] = l1 * p0 + m1 * p1;
            out[b * 3 + 2] = l2 * p0 + m2 * p1;
        }
    }
}

extern "C" void kernel_launch(void* const* d_in, const int* in_sizes, int n_in,
                              void* d_out, int out_size, void* d_ws, size_t ws_size,
                              hipStream_t stream) {
    const float* x      = (const float*)d_in[0];
    const float* adj    = (const float*)d_in[1];
    const int*   midx   = (const int*)  d_in[2];
    const float* gc_w   = (const float*)d_in[3];
    const float* gc_b   = (const float*)d_in[4];
    const float* gc1_w  = (const float*)d_in[5];
    const float* gc1_b  = (const float*)d_in[6];
    const float* gc2_w  = (const float*)d_in[7];
    const float* gc2_b  = (const float*)d_in[8];
    const float* fc1_w  = (const float*)d_in[9];
    const float* fc1_b  = (const float*)d_in[10];
    const float* fc2_w  = (const float*)d_in[11];
    const float* fc2_b  = (const float*)d_in[12];
    const float* cls_w  = (const float*)d_in[13];
    const float* cls_b  = (const float*)d_in[14];
    float* o = (float*)d_out;
    hipLaunchKernelGGL(gnn_mfma, dim3(NBATCH / BPB), dim3(TPB), 0, stream,
        x, adj, midx, gc_w, gc_b, gc1_w, gc1_b, gc2_w, gc2_b,
        fc1_w, fc1_b, fc2_w, fc2_b, cls_w, cls_b, o);
}